// Round 9
// baseline (425.941 us; speedup 1.0000x reference)
//
#include <hip/hip_runtime.h>
#include <float.h>

// ---------------------------------------------------------------------------
// Fused dual-attention (SCA + SSA).  SEQ=1024, B=8, E=512, H=8, HD=64.
//
//  R14 changes:
//   * front_fused SPLIT back into separate proj + gemm launches (fusion
//     measured -50 us: FETCH 276 MB L2 thrash, both roles LDS-hungry).
//   * back_fused (sca || ssa) KEPT — R13 budget arithmetic implies it saved
//     ~40 us vs serial (R13 total ~= R12 despite front costing ~50).
//   * proj keeps R13's no-shadow epilogue (ssa packs bf16 from fp32 P0/P1);
//     ssa keeps SSAV16 + combine-in-gemm_out. All bit-identical math.
// ---------------------------------------------------------------------------

namespace {
constexpr int kSeq = 1024;
constexpr int kBsz = 8;
constexpr int kEmb = 512;
constexpr int kHD  = 64;
constexpr float kT1 = 0.6f;
constexpr float kT2 = 0.4f;
constexpr float kScale = 0.125f;   // 1/sqrt(64), exact pow2
constexpr float kMargin = 0.125f;  // >> 6.5-sigma bf16 score error (~0.018)
constexpr int kCap = 256;          // per-wave candidate list capacity
}

typedef short bf16x8 __attribute__((ext_vector_type(8)));
typedef float f32x4  __attribute__((ext_vector_type(4)));

union FragU { uint4 u4; bf16x8 f; uint u[4]; };

__device__ __forceinline__ ushort f2bf(float f) {
  uint u = __float_as_uint(f);
  u += 0x7fff + ((u >> 16) & 1);        // RNE
  return (ushort)(u >> 16);
}
__device__ __forceinline__ uint pack2(float lo, float hi) {
  return (uint)f2bf(lo) | ((uint)f2bf(hi) << 16);
}
__device__ __forceinline__ float bf2f(uint h) {     // h = low 16 bits
  return __uint_as_float(h << 16);
}
__device__ __forceinline__ uint monokey(float v) {
  uint u = __float_as_uint(v);
  return (u & 0x80000000u) ? ~u : (u | 0x80000000u);
}
__device__ __forceinline__ uint combine2(uint m, uint s) {
  float lo = bf2f(m & 0xFFFF) + kT2 * bf2f(s & 0xFFFF);
  float hi = bf2f(m >> 16)    + kT2 * bf2f(s >> 16);
  return pack2(lo, hi);
}

// ---------------------------------------------------------------------------
// sem_map -> bitmask.  SMASK[t*16 + w] bit j = (SEM[t][w*64+j] >= 0.5)
// ---------------------------------------------------------------------------
__global__ void smask_prep(const float* __restrict__ SEM,
                           unsigned long long* __restrict__ SMASK) {
  const int t = blockIdx.x;
  const int w4 = threadIdx.x >> 6;
  const int lane = threadIdx.x & 63;
#pragma unroll
  for (int i = 0; i < 4; ++i) {
    const int word = (w4 << 2) + i;
    const float v = SEM[t * kSeq + (word << 6) + lane];
    unsigned long long m = __ballot(v >= 0.5f);
    if (lane == 0) SMASK[t * 16 + word] = m;
  }
}

// ---------------------------------------------------------------------------
// fp32 proj GEMM (no shadows) — per-element math byte-identical to R1:
// single accumulator, fma chain k=0..511 ascending, then +bias.
// Tile 128x64, 256 thr, 8x4/thread, BK=32, reg-prefetch.
// grid (64,8,2): z=0 -> query proj, z=1 -> key proj.
// ---------------------------------------------------------------------------
__global__ __launch_bounds__(256, 4) void proj_ns(
    const float* __restrict__ Xq, const float* __restrict__ Xk,
    const float* __restrict__ W, const float* __restrict__ bias,
    float* __restrict__ OutQ, float* __restrict__ OutK)
{
  __shared__ float As[32 * 132];   // [k][m], 128 m + pad 4
  __shared__ float Bs[32 * 68];    // [k][n], 64 n + pad 4

  const int z = blockIdx.z;
  const float* X = z ? Xk : Xq;
  float* Out = z ? OutK : OutQ;
  const int woff = z << 9;

  const int mBase = blockIdx.x << 7;
  const int nBase = blockIdx.y << 6;
  const int tid = threadIdx.x;
  const int tx = tid & 15;
  const int my = tid >> 4;
  const int ar = tid >> 1, ah = (tid & 1) << 4;
  const int br = tid >> 2, bk = (tid & 3) << 3;

  float acc[8][4];
#pragma unroll
  for (int i = 0; i < 8; ++i)
#pragma unroll
    for (int j = 0; j < 4; ++j) acc[i][j] = 0.f;

  const float* xp = X + (size_t)(mBase + ar) * kEmb + ah;
  const float* wp = W + (size_t)(woff + nBase + br) * kEmb + bk;

  float4 a0 = ((const float4*)xp)[0];
  float4 a1 = ((const float4*)xp)[1];
  float4 a2 = ((const float4*)xp)[2];
  float4 a3 = ((const float4*)xp)[3];
  float4 b0 = ((const float4*)wp)[0];
  float4 b1 = ((const float4*)wp)[1];

  for (int k0 = 0; k0 < kEmb; k0 += 32) {
    __syncthreads();
    {
      float av[16] = {a0.x, a0.y, a0.z, a0.w, a1.x, a1.y, a1.z, a1.w,
                      a2.x, a2.y, a2.z, a2.w, a3.x, a3.y, a3.z, a3.w};
#pragma unroll
      for (int i = 0; i < 16; ++i) As[(ah + i) * 132 + ar] = av[i];
      float bv[8] = {b0.x, b0.y, b0.z, b0.w, b1.x, b1.y, b1.z, b1.w};
#pragma unroll
      for (int i = 0; i < 8; ++i) Bs[(bk + i) * 68 + br] = bv[i];
    }
    __syncthreads();

    const int kn = k0 + 32;
    if (kn < kEmb) {
      a0 = ((const float4*)(xp + kn))[0];
      a1 = ((const float4*)(xp + kn))[1];
      a2 = ((const float4*)(xp + kn))[2];
      a3 = ((const float4*)(xp + kn))[3];
      b0 = ((const float4*)(wp + kn))[0];
      b1 = ((const float4*)(wp + kn))[1];
    }

#pragma unroll 8
    for (int k = 0; k < 32; ++k) {
      float4 A0 = *(const float4*)&As[k * 132 + (my << 3)];
      float4 A1 = *(const float4*)&As[k * 132 + (my << 3) + 4];
      float4 Bv = *(const float4*)&Bs[k * 68 + (tx << 2)];
      float aa[8] = {A0.x, A0.y, A0.z, A0.w, A1.x, A1.y, A1.z, A1.w};
      float bb[4] = {Bv.x, Bv.y, Bv.z, Bv.w};
#pragma unroll
      for (int i = 0; i < 8; ++i)
#pragma unroll
        for (int j = 0; j < 4; ++j)
          acc[i][j] = fmaf(aa[i], bb[j], acc[i][j]);
    }
  }

#pragma unroll
  for (int i = 0; i < 8; ++i) {
    const int m = mBase + (my << 3) + i;
#pragma unroll
    for (int j = 0; j < 4; ++j) {
      const int n = nBase + (tx << 2) + j;
      const float v = acc[i][j] + bias[woff + n];
      const int oi = (((m & 7) << 3) + (n >> 6)) * (kSeq * kHD) +
                     ((m >> 3) << 6) + (n & 63);
      Out[oi] = v;
    }
  }
}

// ---------------------------------------------------------------------------
// SCA-proj GEMM (bf16 MFMA): X fp32 -> bf16 headLayout out, grid (64,8,3).
// Tile 128x64, BK=32, 4 waves, stride-20-uint LDS, reg-prefetch.
// ---------------------------------------------------------------------------
__global__ __launch_bounds__(256, 4) void gemm_sca(
    const float* __restrict__ X0, const float* __restrict__ X1,
    const float* __restrict__ X2,
    const float* __restrict__ W, const float* __restrict__ bias,
    ushort* __restrict__ Out16)
{
  __shared__ uint As[128 * 20];
  __shared__ uint Bs[64 * 20];

  const int z = blockIdx.z;
  const float* X = (z == 0) ? X0 : (z == 1) ? X1 : X2;
  const int woff = z << 9;
  const float scale = (z == 0) ? kScale : 1.0f;
  const size_t zoff = (size_t)z * ((size_t)kSeq * kBsz * kEmb);

  const int mBase = blockIdx.x << 7;
  const int nBase = blockIdx.y << 6;
  const int tid = threadIdx.x;
  const int w = tid >> 6;
  const int l = tid & 63;
  const int l15 = l & 15;
  const int quad = l >> 4;
  const int wm = w & 1, wn = w >> 1;

  const int srow = tid >> 1;
  const int shalf = tid & 1;

  f32x4 acc[4][2];
#pragma unroll
  for (int mi = 0; mi < 4; ++mi)
#pragma unroll
    for (int ni = 0; ni < 2; ++ni) acc[mi][ni] = (f32x4){0.f, 0.f, 0.f, 0.f};

  float4 ra0, ra1, ra2, ra3;
  float4 rb0, rb1, rb2, rb3;

#define GLOADF(kk) do {                                                    \
    const float* xp_ = X + (size_t)(mBase + srow) * kEmb + (kk) +          \
                       (shalf << 4);                                       \
    ra0 = ((const float4*)xp_)[0];                                         \
    ra1 = ((const float4*)xp_)[1];                                         \
    ra2 = ((const float4*)xp_)[2];                                         \
    ra3 = ((const float4*)xp_)[3];                                         \
    if (tid < 128) {                                                       \
      const float* wp_ = W + (size_t)(woff + nBase + srow) * kEmb + (kk) + \
                         (shalf << 4);                                     \
      rb0 = ((const float4*)wp_)[0];                                       \
      rb1 = ((const float4*)wp_)[1];                                       \
      rb2 = ((const float4*)wp_)[2];                                       \
      rb3 = ((const float4*)wp_)[3];                                       \
    }                                                                      \
  } while (0)

  GLOADF(0);

  for (int k0 = 0; k0 < kEmb; k0 += 32) {
    uint4 ah0, ah1, bw0, bw1;
    ah0 = make_uint4(pack2(ra0.x, ra0.y), pack2(ra0.z, ra0.w),
                     pack2(ra1.x, ra1.y), pack2(ra1.z, ra1.w));
    ah1 = make_uint4(pack2(ra2.x, ra2.y), pack2(ra2.z, ra2.w),
                     pack2(ra3.x, ra3.y), pack2(ra3.z, ra3.w));
    if (tid < 128) {
      bw0 = make_uint4(pack2(rb0.x, rb0.y), pack2(rb0.z, rb0.w),
                       pack2(rb1.x, rb1.y), pack2(rb1.z, rb1.w));
      bw1 = make_uint4(pack2(rb2.x, rb2.y), pack2(rb2.z, rb2.w),
                       pack2(rb3.x, rb3.y), pack2(rb3.z, rb3.w));
    }
    __syncthreads();
    {
      uint* dst = As + srow * 20 + (shalf << 3);
      ((uint4*)dst)[0] = ah0;
      ((uint4*)dst)[1] = ah1;
      if (tid < 128) {
        uint* db = Bs + srow * 20 + (shalf << 3);
        ((uint4*)db)[0] = bw0;
        ((uint4*)db)[1] = bw1;
      }
    }
    __syncthreads();

    if (k0 + 32 < kEmb) GLOADF(k0 + 32);

    FragU aF[4], bF[2];
#pragma unroll
    for (int ni = 0; ni < 2; ++ni)
      bF[ni].u4 = *(const uint4*)(Bs + ((wn << 5) + (ni << 4) + l15) * 20 + (quad << 2));
#pragma unroll
    for (int mi = 0; mi < 4; ++mi)
      aF[mi].u4 = *(const uint4*)(As + ((wm << 6) + (mi << 4) + l15) * 20 + (quad << 2));
#pragma unroll
    for (int mi = 0; mi < 4; ++mi)
#pragma unroll
      for (int ni = 0; ni < 2; ++ni)
        acc[mi][ni] = __builtin_amdgcn_mfma_f32_16x16x32_bf16(
            aF[mi].f, bF[ni].f, acc[mi][ni], 0, 0, 0);
  }
#undef GLOADF

#pragma unroll
  for (int ni = 0; ni < 2; ++ni) {
    const int n = nBase + (wn << 5) + (ni << 4) + l15;
    const float bv = bias[woff + n];
#pragma unroll
    for (int mi = 0; mi < 4; ++mi) {
#pragma unroll
      for (int r = 0; r < 4; ++r) {
        const int m = mBase + (wm << 6) + (mi << 4) + (quad << 2) + r;
        const float v = acc[mi][ni][r] + bv;
        const int oi = (((m & 7) << 3) + (n >> 6)) * (kSeq * kHD) +
                       ((m >> 3) << 6) + (n & 63);
        Out16[zoff + oi] = f2bf(v * scale);
      }
    }
  }
}

// ---------------------------------------------------------------------------
// SCA body (verbatim R12 math).  LDS: ks[2304] vt[2304] ps[4*576] uints.
// ---------------------------------------------------------------------------
__device__ __forceinline__ void sca_body(
    uint* ks, uint* vt, uint* ps, int idx, int bh,
    const ushort* __restrict__ Q16, const ushort* __restrict__ K16,
    const ushort* __restrict__ V16,
    const unsigned long long* __restrict__ SMASK,
    ushort* __restrict__ MIX16)
{
  const int t0  = idx << 6;
  const int tid = threadIdx.x;
  const int w    = tid >> 6;
  const int l    = tid & 63;
  const int l15  = l & 15;
  const int quad = l >> 4;

  const uint* Qu = (const uint*)Q16 + (size_t)bh * (kSeq * 32);
  const uint* Ku = (const uint*)K16 + (size_t)bh * (kSeq * 32);
  const uint* Vu = (const uint*)V16 + (size_t)bh * (kSeq * 32);

  FragU qf0, qf1;
  {
    const uint* qrow = Qu + (size_t)(t0 + (w << 4) + l15) * 32;
    qf0.u4 = *(const uint4*)(qrow + (quad << 2));
    qf1.u4 = *(const uint4*)(qrow + 16 + (quad << 2));
  }

  f32x4 oacc[4];
#pragma unroll
  for (int nt = 0; nt < 4; ++nt) oacc[nt] = (f32x4){0.f, 0.f, 0.f, 0.f};
  float den[4] = {0.f, 0.f, 0.f, 0.f};

  uint* psw = ps + w * 576;

  const int sl = tid >> 2, c = tid & 3;    // K tile
  const int p = tid >> 3, c7 = tid & 7;    // V tile

  uint4 pk0 = ((const uint4*)(Ku + (size_t)sl * 32 + (c << 3)))[0];
  uint4 pk1 = ((const uint4*)(Ku + (size_t)sl * 32 + (c << 3)))[1];
  uint4 pv0 = *(const uint4*)(Vu + (size_t)(p << 1) * 32 + (c7 << 2));
  uint4 pv1 = *(const uint4*)(Vu + (size_t)(p << 1) * 32 + (c7 << 2) + 32);

  for (int s0 = 0, tile = 0; s0 < kSeq; s0 += 64, ++tile) {
    __syncthreads();
    {
      uint* dst = ks + sl * 36 + (c << 3);
      ((uint4*)dst)[0] = pk0;
      ((uint4*)dst)[1] = pk1;
    }
    {
      FragU A, B;
      A.u4 = pv0;
      B.u4 = pv1;
      const int Wp = (p + ((c7 & 3) << 2)) & 31;
#pragma unroll
      for (int i = 0; i < 8; ++i) {
        uint ai = (A.u[i >> 1] >> ((i & 1) << 4)) & 0xFFFF;
        uint bi = (B.u[i >> 1] >> ((i & 1) << 4)) & 0xFFFF;
        vt[((c7 << 3) + i) * 36 + Wp] = ai | (bi << 16);
      }
    }
    __syncthreads();

    if (s0 + 64 < kSeq) {
      const uint* kp = Ku + (size_t)(s0 + 64 + sl) * 32 + (c << 3);
      pk0 = ((const uint4*)kp)[0];
      pk1 = ((const uint4*)kp)[1];
      const uint* va = Vu + (size_t)(s0 + 64 + (p << 1)) * 32 + (c7 << 2);
      pv0 = *(const uint4*)va;
      pv1 = *(const uint4*)(va + 32);
    }

    unsigned long long wv[4];
#pragma unroll
    for (int r = 0; r < 4; ++r)
      wv[r] = SMASK[(size_t)(t0 + (w << 4) + (quad << 2) + r) * 16 + tile];

#pragma unroll
    for (int st = 0; st < 4; ++st) {
      f32x4 sacc = (f32x4){0.f, 0.f, 0.f, 0.f};
      const int srow = (st << 4) + l15;
      FragU kf0, kf1;
      kf0.u4 = *(const uint4*)(ks + srow * 36 + (quad << 2));
      kf1.u4 = *(const uint4*)(ks + srow * 36 + 16 + (quad << 2));
      sacc = __builtin_amdgcn_mfma_f32_16x16x32_bf16(qf0.f, kf0.f, sacc, 0, 0, 0);
      sacc = __builtin_amdgcn_mfma_f32_16x16x32_bf16(qf1.f, kf1.f, sacc, 0, 0, 0);

#pragma unroll
      for (int r = 0; r < 4; ++r) {
        const int trow = (quad << 2) + r;
        const uint bit = (uint)(wv[r] >> ((st << 4) + l15)) & 1u;
        const float val = bit ? __expf(sacc[r]) : 0.f;
        den[r] += val;
        const int W  = (st << 3) + (l15 >> 1);
        const int Wp = (W + (((trow >> 3) & 1) << 3)) & 31;
        ushort* p16 = (ushort*)(psw + trow * 36 + Wp);
        p16[l15 & 1] = f2bf(val);
      }
    }
#pragma unroll
    for (int ch = 0; ch < 2; ++ch) {
      FragU pf;
      const int pw = ((ch << 4) + (quad << 2) + (((l15 >> 3) & 1) << 3)) & 31;
      pf.u4 = *(const uint4*)(psw + l15 * 36 + pw);
#pragma unroll
      for (int nt = 0; nt < 4; ++nt) {
        const int d = (nt << 4) + l15;
        const int vw = ((ch << 4) + (quad << 2) + (((d >> 3) & 3) << 2)) & 31;
        FragU vf;
        vf.u4 = *(const uint4*)(vt + d * 36 + vw);
        oacc[nt] = __builtin_amdgcn_mfma_f32_16x16x32_bf16(pf.f, vf.f, oacc[nt], 0, 0, 0);
      }
    }
  }

#pragma unroll
  for (int r = 0; r < 4; ++r) {
    float d = den[r];
    d += __shfl_xor(d, 1);
    d += __shfl_xor(d, 2);
    d += __shfl_xor(d, 4);
    d += __shfl_xor(d, 8);
    den[r] = kT1 / d;
  }
  const int b = bh >> 3, h = bh & 7;
#pragma unroll
  for (int nt = 0; nt < 4; ++nt) {
#pragma unroll
    for (int r = 0; r < 4; ++r) {
      const int t = t0 + (w << 4) + (quad << 2) + r;
      const int d = (nt << 4) + l15;
      MIX16[(size_t)(t * kBsz + b) * kEmb + (h << 6) + d] =
          f2bf(oacc[nt][r] * den[r]);
    }
  }
}

// ---------------------------------------------------------------------------
// SSA body, 256-thr (4 waves x 16 rows), grid idx over 16 t-tiles.
// bf16 screen fragments packed on the fly from fp32 P0/P1 (identical bits
// to the old shadows). Argmax'd V rows -> SSAV16 (combined in out-GEMM).
// ---------------------------------------------------------------------------
__device__ __forceinline__ void ssa_body(
    uint* ks, uint2* list2, float* thrL, unsigned long long* key64,
    uint* cnt, int idx, int bh,
    const float* __restrict__ Qf, const float* __restrict__ Kf,
    const ushort* __restrict__ V16,
    const unsigned long long* __restrict__ SMASK,
    ushort* __restrict__ SSAV16)
{
  const int t0  = idx << 6;
  const int tid = threadIdx.x;
  const int w    = tid >> 6;
  const int l    = tid & 63;
  const int l15  = l & 15;
  const int quad = l >> 4;

  if (tid < 4) cnt[tid] = 0;
  if (tid < 64) key64[tid] = 0ull;

  const float* Qh = Qf + (size_t)bh * (kSeq * kHD);
  const float* Kh = Kf + (size_t)bh * (kSeq * kHD);

  FragU qf0, qf1;
  {
    const float* qrow = Qh + (size_t)(t0 + (w << 4) + l15) * kHD;
    float4 q0 = *(const float4*)(qrow + (quad << 3));
    float4 q1 = *(const float4*)(qrow + (quad << 3) + 4);
    float4 q2 = *(const float4*)(qrow + 32 + (quad << 3));
    float4 q3 = *(const float4*)(qrow + 32 + (quad << 3) + 4);
    qf0.u4 = make_uint4(pack2(q0.x * kScale, q0.y * kScale),
                        pack2(q0.z * kScale, q0.w * kScale),
                        pack2(q1.x * kScale, q1.y * kScale),
                        pack2(q1.z * kScale, q1.w * kScale));
    qf1.u4 = make_uint4(pack2(q2.x * kScale, q2.y * kScale),
                        pack2(q2.z * kScale, q2.w * kScale),
                        pack2(q3.x * kScale, q3.y * kScale),
                        pack2(q3.z * kScale, q3.w * kScale));
  }

  float m4[4] = {-FLT_MAX, -FLT_MAX, -FLT_MAX, -FLT_MAX};

  // K staging: thread (sl, c4) packs d = 16*c4 .. +15 of row sl from fp32
  const int sl = tid >> 2, c4 = tid & 3;
  const float* kp = Kh + (size_t)sl * kHD + (c4 << 4);
  float4 pk0 = ((const float4*)kp)[0];
  float4 pk1 = ((const float4*)kp)[1];
  float4 pk2 = ((const float4*)kp)[2];
  float4 pk3 = ((const float4*)kp)[3];

  for (int s0 = 0, tile = 0; s0 < kSeq; s0 += 64, ++tile) {
    __syncthreads();
    {
      uint4 w0 = make_uint4(pack2(pk0.x, pk0.y), pack2(pk0.z, pk0.w),
                            pack2(pk1.x, pk1.y), pack2(pk1.z, pk1.w));
      uint4 w1 = make_uint4(pack2(pk2.x, pk2.y), pack2(pk2.z, pk2.w),
                            pack2(pk3.x, pk3.y), pack2(pk3.z, pk3.w));
      uint* dst = ks + sl * 36 + (c4 << 3);
      ((uint4*)dst)[0] = w0;
      ((uint4*)dst)[1] = w1;
    }
    __syncthreads();

    if (s0 + 64 < kSeq) {
      const float* kn = Kh + (size_t)(s0 + 64 + sl) * kHD + (c4 << 4);
      pk0 = ((const float4*)kn)[0];
      pk1 = ((const float4*)kn)[1];
      pk2 = ((const float4*)kn)[2];
      pk3 = ((const float4*)kn)[3];
    }

    unsigned long long wv[4];
#pragma unroll
    for (int r = 0; r < 4; ++r)
      wv[r] = SMASK[(size_t)(t0 + (w << 4) + (quad << 2) + r) * 16 + tile];

    f32x4 sv[4];
#pragma unroll
    for (int st = 0; st < 4; ++st) {
      f32x4 sacc = (f32x4){0.f, 0.f, 0.f, 0.f};
      const int srow = (st << 4) + l15;
      FragU kf0, kf1;
      kf0.u4 = *(const uint4*)(ks + srow * 36 + (quad << 2));
      kf1.u4 = *(const uint4*)(ks + srow * 36 + 16 + (quad << 2));
      sacc = __builtin_amdgcn_mfma_f32_16x16x32_bf16(qf0.f, kf0.f, sacc, 0, 0, 0);
      sacc = __builtin_amdgcn_mfma_f32_16x16x32_bf16(qf1.f, kf1.f, sacc, 0, 0, 0);
      sv[st] = sacc;
#pragma unroll
      for (int r = 0; r < 4; ++r) {
        const uint bit = (uint)(wv[r] >> ((st << 4) + l15)) & 1u;
        if (bit) m4[r] = fmaxf(m4[r], sacc[r]);
      }
    }
#pragma unroll
    for (int r = 0; r < 4; ++r) {
      float m = m4[r];
      m = fmaxf(m, __shfl_xor(m, 1));
      m = fmaxf(m, __shfl_xor(m, 2));
      m = fmaxf(m, __shfl_xor(m, 4));
      m = fmaxf(m, __shfl_xor(m, 8));
      m4[r] = m;
    }
#pragma unroll
    for (int st = 0; st < 4; ++st) {
#pragma unroll
      for (int r = 0; r < 4; ++r) {
        const uint bit = (uint)(wv[r] >> ((st << 4) + l15)) & 1u;
        const float x = sv[st][r];
        if (bit && x >= m4[r] - kMargin) {
          uint idx2 = atomicAdd(&cnt[w], 1u);
          if (idx2 < (uint)kCap) {
            const int rowid = (quad << 2) + r;
            const int s = s0 + (st << 4) + l15;
            list2[w * kCap + idx2] = make_uint2(__float_as_uint(x),
                                                ((uint)rowid << 10) | (uint)s);
          }
        }
      }
    }
  }

  if (l15 == 0) {
#pragma unroll
    for (int r = 0; r < 4; ++r) thrL[w * 16 + (quad << 2) + r] = m4[r] - kMargin;
  }
  __syncthreads();

  const uint n = min(cnt[w], (uint)kCap);
  for (uint base = 0; base < n; base += 64) {
    const uint e = base + (uint)l;
    if (e < n) {
      const uint2 ent = list2[w * kCap + e];
      const uint rowid = ent.y >> 10;
      const uint s = ent.y & 1023u;
      const float xv = __uint_as_float(ent.x);
      if (xv >= thrL[w * 16 + rowid]) {
        const int t = t0 + (w << 4) + (int)rowid;
        const float* qe = Qh + (size_t)t * kHD;
        const float* ke = Kh + (size_t)s * kHD;
        float p0 = 0.f, p1 = 0.f, p2 = 0.f, p3 = 0.f;
#pragma unroll
        for (int i = 0; i < 16; ++i) {
          float4 qq = *(const float4*)(qe + (i << 2));
          float4 kk = *(const float4*)(ke + (i << 2));
          p0 = fmaf(qq.x, kk.x, p0);
          p1 = fmaf(qq.y, kk.y, p1);
          p2 = fmaf(qq.z, kk.z, p2);
          p3 = fmaf(qq.w, kk.w, p3);
        }
        const float acc = ((p0 + p1) + (p2 + p3)) * kScale;
        const unsigned long long key =
            ((unsigned long long)monokey(acc) << 16) |
            (unsigned long long)(1023u - s);
        atomicMax(&key64[w * 16 + rowid], key);
      }
    }
  }
  __syncthreads();

  // store raw argmax'd V rows (bf16) to SSAV16; combine happens in out-GEMM
  const int b = bh >> 3, h = bh & 7;
  const uint* Vu = (const uint*)V16 + (size_t)bh * (kSeq * 32);
#pragma unroll
  for (int r = 0; r < 4; ++r) {
    const int rowid = (quad << 2) + r;
    const unsigned long long key = key64[w * 16 + rowid];
    const uint s = 1023u - (uint)(key & 0xFFFFull);
    const uint2 vv = *(const uint2*)(Vu + (size_t)s * 32 + (l15 << 1));
    const int t = t0 + (w << 4) + rowid;
    uint* op = (uint*)SSAV16 + ((size_t)(t * kBsz + b) * kEmb + (h << 6)) / 2 + (l15 << 1);
    *(uint2*)op = vv;
  }
}

// ---------------------------------------------------------------------------
// BACK fused: grid (32, 64); x even -> sca tile x/2, x odd -> ssa tile x/2.
// LDS overlay 27648 B (sca 6912 uints; ssa 4548 uints).
// ---------------------------------------------------------------------------
__global__ __launch_bounds__(256, 4) void back_fused(
    const ushort* __restrict__ Q16, const ushort* __restrict__ K16,
    const ushort* __restrict__ V16,
    const float* __restrict__ P0, const float* __restrict__ P1,
    const unsigned long long* __restrict__ SMASK,
    ushort* __restrict__ MIX16, ushort* __restrict__ SSAV16)
{
  __shared__ unsigned long long lds8[3456];   // 27648 B, 8-aligned
  uint* base = (uint*)lds8;

  const int role = blockIdx.x & 1;
  const int idx  = blockIdx.x >> 1;
  const int bh   = blockIdx.y;

  if (role == 0) {
    sca_body(base, base + 2304, base + 4608, idx, bh,
             Q16, K16, V16, SMASK, MIX16);
  } else {
    ssa_body(base, (uint2*)(base + 2304), (float*)(base + 4352),
             (unsigned long long*)(base + 4416), base + 4544,
             idx, bh, P0, P1, V16, SMASK, SSAV16);
  }
}

// ---------------------------------------------------------------------------
// Out-projection GEMM: X = bf16(bf2f(MIX16) + T2*bf2f(SSAV16)) staged on the
// fly (identical fp32 ops to the old ssa gather), W=Wo, fp32 out.
// ---------------------------------------------------------------------------
__global__ __launch_bounds__(256, 4) void gemm_out(
    const ushort* __restrict__ MIX16, const ushort* __restrict__ SSAV16,
    const float* __restrict__ W, const float* __restrict__ bias,
    float* __restrict__ OutF)
{
  __shared__ uint As[128 * 20];
  __shared__ uint Bs[64 * 20];

  const int mBase = blockIdx.x << 7;
  const int nBase = blockIdx.y << 6;
  const int tid = threadIdx.x;
  const int w = tid >> 6;
  const int l = tid & 63;
  const int l15 = l & 15;
  const int quad = l >> 4;
  const int wm = w & 1, wn = w >> 1;

  const int srow = tid >> 1;
  const int shalf = tid & 1;

  f32x4 acc[4][2];
#pragma unroll
  for (int mi = 0; mi < 4; ++mi)
#pragma unroll
    for (int ni = 0; ni < 2; ++ni) acc[mi][ni] = (f32x4){0.f, 0.f, 0.f, 0.f};

  uint4 qa0, qa1, qb0, qb1;
  float4 rb0, rb1, rb2, rb3;

#define GLOADO(kk) do {                                                    \
    const size_t off_ = (size_t)(mBase + srow) * 256 + ((kk) >> 1) +       \
                        (shalf << 3);                                      \
    const uint* ma_ = (const uint*)MIX16 + off_;                           \
    qa0 = ((const uint4*)ma_)[0];                                          \
    qa1 = ((const uint4*)ma_)[1];                                          \
    const uint* sa_ = (const uint*)SSAV16 + off_;                          \
    qb0 = ((const uint4*)sa_)[0];                                          \
    qb1 = ((const uint4*)sa_)[1];                                          \
    if (tid < 128) {                                                       \
      const float* wp_ = W + (size_t)(nBase + srow) * kEmb + (kk) +        \
                         (shalf << 4);                                     \
      rb0 = ((const float4*)wp_)[0];                                       \
      rb1 = ((const float4*)wp_)[1];                                       \
      rb2 = ((const float4*)wp_)[2];                                       \
      rb3 = ((const float4*)wp_)[3];                                       \
    }                                                                      \
  } while (0)

  GLOADO(0);

  for (int k0 = 0; k0 < kEmb; k0 += 32) {
    uint4 ah0, ah1, bw0, bw1;
    ah0 = make_uint4(combine2(qa0.x, qb0.x), combine2(qa0.y, qb0.y),
                     combine2(qa0.z, qb0.z), combine2(qa0.w, qb0.w));
    ah1 = make_uint4(combine2(qa1.x, qb1.x), combine2(qa1.y, qb1.y),
                     combine2(qa1.z, qb1.z), combine2(qa1.w, qb1.w));
    if (tid < 128) {
      bw0 = make_uint4(pack2(rb0.x, rb0.y), pack2(rb0.z, rb0.w),
                       pack2(rb1.x, rb1.y), pack2(rb1.z, rb1.w));
      bw1 = make_uint4(pack2(rb2.x, rb2.y), pack2(rb2.z, rb2.w),
                       pack2(rb3.x, rb3.y), pack2(rb3.z, rb3.w));
    }
    __syncthreads();
    {
      uint* dst = As + srow * 20 + (shalf << 3);
      ((uint4*)dst)[0] = ah0;
      ((uint4*)dst)[1] = ah1;
      if (tid < 128) {
        uint* db = Bs + srow * 20 + (shalf << 3);
        ((uint4*)db)[0] = bw0;
        ((uint4*)db)[1] = bw1;
      }
    }
    __syncthreads();

    if (k0 + 32 < kEmb) GLOADO(k0 + 32);

    FragU aF[4], bF[2];
#pragma unroll
    for (int ni = 0; ni < 2; ++ni)
      bF[ni].u4 = *(const uint4*)(Bs + ((wn << 5) + (ni << 4) + l15) * 20 + (quad << 2));
#pragma unroll
    for (int mi = 0; mi < 4; ++mi)
      aF[mi].u4 = *(const uint4*)(As + ((wm << 6) + (mi << 4) + l15) * 20 + (quad << 2));
#pragma unroll
    for (int mi = 0; mi < 4; ++mi)
#pragma unroll
      for (int ni = 0; ni < 2; ++ni)
        acc[mi][ni] = __builtin_amdgcn_mfma_f32_16x16x32_bf16(
            aF[mi].f, bF[ni].f, acc[mi][ni], 0, 0, 0);
  }
#undef GLOADO

#pragma unroll
  for (int ni = 0; ni < 2; ++ni) {
    const int n = nBase + (wn << 5) + (ni << 4) + l15;
    const float bv = bias[n];
#pragma unroll
    for (int mi = 0; mi < 4; ++mi) {
#pragma unroll
      for (int r = 0; r < 4; ++r) {
        const int m = mBase + (wm << 6) + (mi << 4) + (quad << 2) + r;
        const float v = acc[mi][ni][r] + bv;
        OutF[(size_t)m * kEmb + n] = v;
      }
    }
  }
}

extern "C" void kernel_launch(void* const* d_in, const int* in_sizes, int n_in,
                              void* d_out, int out_size, void* d_ws, size_t ws_size,
                              hipStream_t stream) {
  const float* query  = (const float*)d_in[0];
  const float* key    = (const float*)d_in[1];
  const float* value  = (const float*)d_in[2];
  const float* qsem   = (const float*)d_in[3];
  const float* ksem   = (const float*)d_in[4];
  const float* semmap = (const float*)d_in[5];
  const float* Wi     = (const float*)d_in[6];
  const float* bi     = (const float*)d_in[7];
  const float* Wo     = (const float*)d_in[8];
  const float* bo     = (const float*)d_in[9];
  float* out = (float*)d_out;

  char* ws = (char*)d_ws;
  unsigned long long* SMASK = (unsigned long long*)ws;           ws += 1024 * 16 * 8;
  ushort* Q16   = (ushort*)ws; ws += (size_t)64 * kSeq * kHD * 2;   // 8 MB
  ushort* K16   = (ushort*)ws; ws += (size_t)64 * kSeq * kHD * 2;   // 8 MB
  ushort* V16   = (ushort*)ws; ws += (size_t)64 * kSeq * kHD * 2;   // 8 MB
  ushort* MIX16 = (ushort*)ws; ws += (size_t)kSeq * kBsz * kEmb * 2; // 8 MB
  ushort* SSAV16= (ushort*)ws; ws += (size_t)kSeq * kBsz * kEmb * 2; // 8 MB
  float* P1 = (float*)ws;      ws += (size_t)64 * kSeq * kHD * 4;   // 16 MB
  float* P0 = out;   // d_out is dead until gemm_out: use as fp32 Q proj

  const dim3 gp(64, 8, 2);   // fp32 proj grid (128x64 tiles, z = q/k)
  const dim3 g3(64, 8, 3);   // bf16 gemm grid, z = qsem/ksem/value

  smask_prep<<<1024, 256, 0, stream>>>(semmap, SMASK);
  // SCA projections (bf16 MFMA), merged q/k/v in one launch
  gemm_sca<<<g3, 256, 0, stream>>>(qsem, ksem, value, Wi, bi, Q16);
  // SSA fp32 projections (no shadows; ssa packs bf16 on the fly)
  proj_ns<<<gp, 256, 0, stream>>>(query, key, Wi, bi, P0, P1);
  // SCA attention (-> MIX16) interleaved with SSA screen+verify (-> SSAV16)
  back_fused<<<dim3(32, 64), 256, 0, stream>>>(Q16, K16, V16, P0, P1,
                                               SMASK, MIX16, SSAV16);
  // Out projection; combines MIX16 + T2*SSAV16 at staging
  gemm_out<<<dim3(64, 8), 256, 0, stream>>>(MIX16, SSAV16, Wo, bo, out);
}

// Round 10
// 401.314 us; speedup vs baseline: 1.0614x; 1.0614x over previous
//
#include <hip/hip_runtime.h>
#include <float.h>

// ---------------------------------------------------------------------------
// Fused dual-attention (SCA + SSA).  SEQ=1024, B=8, E=512, H=8, HD=64.
//
//  R15 changes:
//   * back_fused REVERTED to R12's serial sca (256thr) + 512-thr ssa with
//     RMW-MIX16 gather (R12 vs R14 totals isolated back-fusion at +23 us).
//     ssa now packs its bf16 screen Q/K from fp32 P0/P1 on the fly
//     (bit-identical to the old shadows) -> no-shadow proj win kept.
//   * NEW prepack kernel: qsem/ksem/value + Wi + Wo fp32 -> bf16 ONCE
//     (~80 MB HBM, ~13 us). gemm_sca was staging-pack-bound (X re-packed
//     8x, Wi re-packed 64x, ~32 pack2 per thread per chunk vs 8 MFMA);
//     staging is now direct uint4 copies. Same RNE f2bf -> identical bits.
//   * X16 (24 MB) memory-overlaps P1 (16 MB): gemm_sca (reads X16) is
//     stream-ordered before proj (writes P1).
// ---------------------------------------------------------------------------

namespace {
constexpr int kSeq = 1024;
constexpr int kBsz = 8;
constexpr int kEmb = 512;
constexpr int kHD  = 64;
constexpr float kT1 = 0.6f;
constexpr float kT2 = 0.4f;
constexpr float kScale = 0.125f;   // 1/sqrt(64), exact pow2
constexpr float kMargin = 0.125f;  // >> 6.5-sigma bf16 score error (~0.018)
constexpr int kCap = 256;          // per-wave candidate list capacity
}

typedef short bf16x8 __attribute__((ext_vector_type(8)));
typedef float f32x4  __attribute__((ext_vector_type(4)));

union FragU { uint4 u4; bf16x8 f; uint u[4]; };

__device__ __forceinline__ ushort f2bf(float f) {
  uint u = __float_as_uint(f);
  u += 0x7fff + ((u >> 16) & 1);        // RNE
  return (ushort)(u >> 16);
}
__device__ __forceinline__ uint pack2(float lo, float hi) {
  return (uint)f2bf(lo) | ((uint)f2bf(hi) << 16);
}
__device__ __forceinline__ float bf2f(uint h) {     // h = low 16 bits
  return __uint_as_float(h << 16);
}
__device__ __forceinline__ uint monokey(float v) {
  uint u = __float_as_uint(v);
  return (u & 0x80000000u) ? ~u : (u | 0x80000000u);
}

// ---------------------------------------------------------------------------
// prepack: fp32 -> bf16 (RNE, identical bits to in-kernel pack).
// z 0..2: X inputs (4194304 f each); z=3: Wi (786432); z=4: Wo (262144).
// ---------------------------------------------------------------------------
__global__ __launch_bounds__(256, 8) void prepack(
    const float* __restrict__ X0, const float* __restrict__ X1,
    const float* __restrict__ X2, const float* __restrict__ Wif,
    const float* __restrict__ Wof,
    ushort* __restrict__ X16, ushort* __restrict__ Wi16,
    ushort* __restrict__ Wo16)
{
  const int z = blockIdx.y;
  const float* src;
  ushort* dst;
  size_t count;
  if (z == 0)      { src = X0;  dst = X16;                count = 4194304; }
  else if (z == 1) { src = X1;  dst = X16 + 4194304;      count = 4194304; }
  else if (z == 2) { src = X2;  dst = X16 + 2 * 4194304;  count = 4194304; }
  else if (z == 3) { src = Wif; dst = Wi16;               count = 786432; }
  else             { src = Wof; dst = Wo16;               count = 262144; }

  const size_t idx = ((size_t)blockIdx.x * 256 + threadIdx.x) * 8;
  if (idx >= count) return;
  float4 f0 = *(const float4*)(src + idx);
  float4 f1 = *(const float4*)(src + idx + 4);
  uint4 o = make_uint4(pack2(f0.x, f0.y), pack2(f0.z, f0.w),
                       pack2(f1.x, f1.y), pack2(f1.z, f1.w));
  *(uint4*)(dst + idx) = o;
}

// ---------------------------------------------------------------------------
// sem_map -> bitmask.  SMASK[t*16 + w] bit j = (SEM[t][w*64+j] >= 0.5)
// ---------------------------------------------------------------------------
__global__ void smask_prep(const float* __restrict__ SEM,
                           unsigned long long* __restrict__ SMASK) {
  const int t = blockIdx.x;
  const int w4 = threadIdx.x >> 6;
  const int lane = threadIdx.x & 63;
#pragma unroll
  for (int i = 0; i < 4; ++i) {
    const int word = (w4 << 2) + i;
    const float v = SEM[t * kSeq + (word << 6) + lane];
    unsigned long long m = __ballot(v >= 0.5f);
    if (lane == 0) SMASK[t * 16 + word] = m;
  }
}

// ---------------------------------------------------------------------------
// fp32 proj GEMM (no shadows) — per-element math byte-identical to R1:
// single accumulator, fma chain k=0..511 ascending, then +bias.
// Tile 128x64, 256 thr, 8x4/thread, BK=32, reg-prefetch. grid (64,8,2).
// [R14 harness-verified: 124.8 us]
// ---------------------------------------------------------------------------
__global__ __launch_bounds__(256, 4) void proj_ns(
    const float* __restrict__ Xq, const float* __restrict__ Xk,
    const float* __restrict__ W, const float* __restrict__ bias,
    float* __restrict__ OutQ, float* __restrict__ OutK)
{
  __shared__ float As[32 * 132];   // [k][m], 128 m + pad 4
  __shared__ float Bs[32 * 68];    // [k][n], 64 n + pad 4

  const int z = blockIdx.z;
  const float* X = z ? Xk : Xq;
  float* Out = z ? OutK : OutQ;
  const int woff = z << 9;

  const int mBase = blockIdx.x << 7;
  const int nBase = blockIdx.y << 6;
  const int tid = threadIdx.x;
  const int tx = tid & 15;
  const int my = tid >> 4;
  const int ar = tid >> 1, ah = (tid & 1) << 4;
  const int br = tid >> 2, bk = (tid & 3) << 3;

  float acc[8][4];
#pragma unroll
  for (int i = 0; i < 8; ++i)
#pragma unroll
    for (int j = 0; j < 4; ++j) acc[i][j] = 0.f;

  const float* xp = X + (size_t)(mBase + ar) * kEmb + ah;
  const float* wp = W + (size_t)(woff + nBase + br) * kEmb + bk;

  float4 a0 = ((const float4*)xp)[0];
  float4 a1 = ((const float4*)xp)[1];
  float4 a2 = ((const float4*)xp)[2];
  float4 a3 = ((const float4*)xp)[3];
  float4 b0 = ((const float4*)wp)[0];
  float4 b1 = ((const float4*)wp)[1];

  for (int k0 = 0; k0 < kEmb; k0 += 32) {
    __syncthreads();
    {
      float av[16] = {a0.x, a0.y, a0.z, a0.w, a1.x, a1.y, a1.z, a1.w,
                      a2.x, a2.y, a2.z, a2.w, a3.x, a3.y, a3.z, a3.w};
#pragma unroll
      for (int i = 0; i < 16; ++i) As[(ah + i) * 132 + ar] = av[i];
      float bv[8] = {b0.x, b0.y, b0.z, b0.w, b1.x, b1.y, b1.z, b1.w};
#pragma unroll
      for (int i = 0; i < 8; ++i) Bs[(bk + i) * 68 + br] = bv[i];
    }
    __syncthreads();

    const int kn = k0 + 32;
    if (kn < kEmb) {
      a0 = ((const float4*)(xp + kn))[0];
      a1 = ((const float4*)(xp + kn))[1];
      a2 = ((const float4*)(xp + kn))[2];
      a3 = ((const float4*)(xp + kn))[3];
      b0 = ((const float4*)(wp + kn))[0];
      b1 = ((const float4*)(wp + kn))[1];
    }

#pragma unroll 8
    for (int k = 0; k < 32; ++k) {
      float4 A0 = *(const float4*)&As[k * 132 + (my << 3)];
      float4 A1 = *(const float4*)&As[k * 132 + (my << 3) + 4];
      float4 Bv = *(const float4*)&Bs[k * 68 + (tx << 2)];
      float aa[8] = {A0.x, A0.y, A0.z, A0.w, A1.x, A1.y, A1.z, A1.w};
      float bb[4] = {Bv.x, Bv.y, Bv.z, Bv.w};
#pragma unroll
      for (int i = 0; i < 8; ++i)
#pragma unroll
        for (int j = 0; j < 4; ++j)
          acc[i][j] = fmaf(aa[i], bb[j], acc[i][j]);
    }
  }

#pragma unroll
  for (int i = 0; i < 8; ++i) {
    const int m = mBase + (my << 3) + i;
#pragma unroll
    for (int j = 0; j < 4; ++j) {
      const int n = nBase + (tx << 2) + j;
      const float v = acc[i][j] + bias[woff + n];
      const int oi = (((m & 7) << 3) + (n >> 6)) * (kSeq * kHD) +
                     ((m >> 3) << 6) + (n & 63);
      Out[oi] = v;
    }
  }
}

// ---------------------------------------------------------------------------
// SCA-proj GEMM (bf16 MFMA): A from pre-packed X16 slab z, B from Wi16.
// All staging = direct uint4 copies. Tile 128x64, BK=32, 4 waves.
// grid (64,8,3). Output bf16 headLayout (z=0 scaled by kScale).
// ---------------------------------------------------------------------------
__global__ __launch_bounds__(256, 4) void gemm_sca16(
    const ushort* __restrict__ X16, const ushort* __restrict__ Wi16,
    const float* __restrict__ bias, ushort* __restrict__ Out16)
{
  __shared__ uint As[128 * 20];
  __shared__ uint Bs[64 * 20];

  const int z = blockIdx.z;
  const int woff = z << 9;
  const float scale = (z == 0) ? kScale : 1.0f;
  const size_t zoff = (size_t)z * ((size_t)kSeq * kBsz * kEmb);
  const uint* Xu = (const uint*)X16 + (size_t)z * (8192 * 256);
  const uint* Wu = (const uint*)Wi16;

  const int mBase = blockIdx.x << 7;
  const int nBase = blockIdx.y << 6;
  const int tid = threadIdx.x;
  const int w = tid >> 6;
  const int l = tid & 63;
  const int l15 = l & 15;
  const int quad = l >> 4;
  const int wm = w & 1, wn = w >> 1;

  const int srow = tid >> 1;
  const int shalf = tid & 1;

  f32x4 acc[4][2];
#pragma unroll
  for (int mi = 0; mi < 4; ++mi)
#pragma unroll
    for (int ni = 0; ni < 2; ++ni) acc[mi][ni] = (f32x4){0.f, 0.f, 0.f, 0.f};

  uint4 qa0, qa1, qb0, qb1;

#define GLOAD16(kk) do {                                                   \
    const uint* xs_ = Xu + (size_t)(mBase + srow) * 256 + ((kk) >> 1) +    \
                      (shalf << 3);                                        \
    qa0 = ((const uint4*)xs_)[0];                                          \
    qa1 = ((const uint4*)xs_)[1];                                          \
    if (tid < 128) {                                                       \
      const uint* ws_ = Wu + (size_t)(woff + nBase + srow) * 256 +         \
                        ((kk) >> 1) + (shalf << 3);                        \
      qb0 = ((const uint4*)ws_)[0];                                        \
      qb1 = ((const uint4*)ws_)[1];                                        \
    }                                                                      \
  } while (0)

  GLOAD16(0);

  for (int k0 = 0; k0 < kEmb; k0 += 32) {
    uint4 ah0 = qa0, ah1 = qa1, bw0 = qb0, bw1 = qb1;
    __syncthreads();
    {
      uint* dst = As + srow * 20 + (shalf << 3);
      ((uint4*)dst)[0] = ah0;
      ((uint4*)dst)[1] = ah1;
      if (tid < 128) {
        uint* db = Bs + srow * 20 + (shalf << 3);
        ((uint4*)db)[0] = bw0;
        ((uint4*)db)[1] = bw1;
      }
    }
    __syncthreads();

    if (k0 + 32 < kEmb) GLOAD16(k0 + 32);

    FragU aF[4], bF[2];
#pragma unroll
    for (int ni = 0; ni < 2; ++ni)
      bF[ni].u4 = *(const uint4*)(Bs + ((wn << 5) + (ni << 4) + l15) * 20 + (quad << 2));
#pragma unroll
    for (int mi = 0; mi < 4; ++mi)
      aF[mi].u4 = *(const uint4*)(As + ((wm << 6) + (mi << 4) + l15) * 20 + (quad << 2));
#pragma unroll
    for (int mi = 0; mi < 4; ++mi)
#pragma unroll
      for (int ni = 0; ni < 2; ++ni)
        acc[mi][ni] = __builtin_amdgcn_mfma_f32_16x16x32_bf16(
            aF[mi].f, bF[ni].f, acc[mi][ni], 0, 0, 0);
  }
#undef GLOAD16

#pragma unroll
  for (int ni = 0; ni < 2; ++ni) {
    const int n = nBase + (wn << 5) + (ni << 4) + l15;
    const float bv = bias[woff + n];
#pragma unroll
    for (int mi = 0; mi < 4; ++mi) {
#pragma unroll
      for (int r = 0; r < 4; ++r) {
        const int m = mBase + (wm << 6) + (mi << 4) + (quad << 2) + r;
        const float v = acc[mi][ni][r] + bv;
        const int oi = (((m & 7) << 3) + (n >> 6)) * (kSeq * kHD) +
                       ((m >> 3) << 6) + (n & 63);
        Out16[zoff + oi] = f2bf(v * scale);
      }
    }
  }
}

// ---------------------------------------------------------------------------
// SCA: bf16 Q16 (pre-scaled) / K16 / V16, SMASK bits, MIX16 out.
// [R12 harness-verified body]  grid (16,64), 256 thr.
// ---------------------------------------------------------------------------
__global__ __launch_bounds__(256, 4) void sca_mfma2(
    const ushort* __restrict__ Q16, const ushort* __restrict__ K16,
    const ushort* __restrict__ V16,
    const unsigned long long* __restrict__ SMASK,
    ushort* __restrict__ MIX16)
{
  __shared__ uint ks[64 * 36];
  __shared__ uint vt[64 * 36];
  __shared__ uint ps[4][16 * 36];

  const int t0  = blockIdx.x << 6;
  const int bh  = blockIdx.y;
  const int tid = threadIdx.x;
  const int w    = tid >> 6;
  const int l    = tid & 63;
  const int l15  = l & 15;
  const int quad = l >> 4;

  const uint* Qu = (const uint*)Q16 + (size_t)bh * (kSeq * 32);
  const uint* Ku = (const uint*)K16 + (size_t)bh * (kSeq * 32);
  const uint* Vu = (const uint*)V16 + (size_t)bh * (kSeq * 32);

  FragU qf0, qf1;
  {
    const uint* qrow = Qu + (size_t)(t0 + (w << 4) + l15) * 32;
    qf0.u4 = *(const uint4*)(qrow + (quad << 2));
    qf1.u4 = *(const uint4*)(qrow + 16 + (quad << 2));
  }

  f32x4 oacc[4];
#pragma unroll
  for (int nt = 0; nt < 4; ++nt) oacc[nt] = (f32x4){0.f, 0.f, 0.f, 0.f};
  float den[4] = {0.f, 0.f, 0.f, 0.f};

  uint* psw = ps[w];

  const int sl = tid >> 2, c = tid & 3;    // K tile
  const int p = tid >> 3, c7 = tid & 7;    // V tile

  uint4 pk0 = ((const uint4*)(Ku + (size_t)sl * 32 + (c << 3)))[0];
  uint4 pk1 = ((const uint4*)(Ku + (size_t)sl * 32 + (c << 3)))[1];
  uint4 pv0 = *(const uint4*)(Vu + (size_t)(p << 1) * 32 + (c7 << 2));
  uint4 pv1 = *(const uint4*)(Vu + (size_t)(p << 1) * 32 + (c7 << 2) + 32);

  for (int s0 = 0, tile = 0; s0 < kSeq; s0 += 64, ++tile) {
    __syncthreads();
    {
      uint* dst = ks + sl * 36 + (c << 3);
      ((uint4*)dst)[0] = pk0;
      ((uint4*)dst)[1] = pk1;
    }
    {
      FragU A, B;
      A.u4 = pv0;
      B.u4 = pv1;
      const int Wp = (p + ((c7 & 3) << 2)) & 31;
#pragma unroll
      for (int i = 0; i < 8; ++i) {
        uint ai = (A.u[i >> 1] >> ((i & 1) << 4)) & 0xFFFF;
        uint bi = (B.u[i >> 1] >> ((i & 1) << 4)) & 0xFFFF;
        vt[((c7 << 3) + i) * 36 + Wp] = ai | (bi << 16);
      }
    }
    __syncthreads();

    if (s0 + 64 < kSeq) {
      const uint* kp = Ku + (size_t)(s0 + 64 + sl) * 32 + (c << 3);
      pk0 = ((const uint4*)kp)[0];
      pk1 = ((const uint4*)kp)[1];
      const uint* va = Vu + (size_t)(s0 + 64 + (p << 1)) * 32 + (c7 << 2);
      pv0 = *(const uint4*)va;
      pv1 = *(const uint4*)(va + 32);
    }

    unsigned long long wv[4];
#pragma unroll
    for (int r = 0; r < 4; ++r)
      wv[r] = SMASK[(size_t)(t0 + (w << 4) + (quad << 2) + r) * 16 + tile];

#pragma unroll
    for (int st = 0; st < 4; ++st) {
      f32x4 sacc = (f32x4){0.f, 0.f, 0.f, 0.f};
      const int srow = (st << 4) + l15;
      FragU kf0, kf1;
      kf0.u4 = *(const uint4*)(ks + srow * 36 + (quad << 2));
      kf1.u4 = *(const uint4*)(ks + srow * 36 + 16 + (quad << 2));
      sacc = __builtin_amdgcn_mfma_f32_16x16x32_bf16(qf0.f, kf0.f, sacc, 0, 0, 0);
      sacc = __builtin_amdgcn_mfma_f32_16x16x32_bf16(qf1.f, kf1.f, sacc, 0, 0, 0);

#pragma unroll
      for (int r = 0; r < 4; ++r) {
        const int trow = (quad << 2) + r;
        const uint bit = (uint)(wv[r] >> ((st << 4) + l15)) & 1u;
        const float val = bit ? __expf(sacc[r]) : 0.f;
        den[r] += val;
        const int W  = (st << 3) + (l15 >> 1);
        const int Wp = (W + (((trow >> 3) & 1) << 3)) & 31;
        ushort* p16 = (ushort*)(psw + trow * 36 + Wp);
        p16[l15 & 1] = f2bf(val);
      }
    }
#pragma unroll
    for (int ch = 0; ch < 2; ++ch) {
      FragU pf;
      const int pw = ((ch << 4) + (quad << 2) + (((l15 >> 3) & 1) << 3)) & 31;
      pf.u4 = *(const uint4*)(psw + l15 * 36 + pw);
#pragma unroll
      for (int nt = 0; nt < 4; ++nt) {
        const int d = (nt << 4) + l15;
        const int vw = ((ch << 4) + (quad << 2) + (((d >> 3) & 3) << 2)) & 31;
        FragU vf;
        vf.u4 = *(const uint4*)(vt + d * 36 + vw);
        oacc[nt] = __builtin_amdgcn_mfma_f32_16x16x32_bf16(pf.f, vf.f, oacc[nt], 0, 0, 0);
      }
    }
  }

#pragma unroll
  for (int r = 0; r < 4; ++r) {
    float d = den[r];
    d += __shfl_xor(d, 1);
    d += __shfl_xor(d, 2);
    d += __shfl_xor(d, 4);
    d += __shfl_xor(d, 8);
    den[r] = kT1 / d;
  }
  const int b = bh >> 3, h = bh & 7;
#pragma unroll
  for (int nt = 0; nt < 4; ++nt) {
#pragma unroll
    for (int r = 0; r < 4; ++r) {
      const int t = t0 + (w << 4) + (quad << 2) + r;
      const int d = (nt << 4) + l15;
      MIX16[(size_t)(t * kBsz + b) * kEmb + (h << 6) + d] =
          f2bf(oacc[nt][r] * den[r]);
    }
  }
}

// ---------------------------------------------------------------------------
// SSA single-pass (R12 512-thr structure): bf16 MFMA screen with running
// cross-lane max; Q/K screen fragments packed on the fly from fp32 P0/P1
// (identical bits to the old shadows); survivors get the exact fp32 dot in
// R1's order; per-row resolve via 64-bit atomicMax; RMW gather into MIX16.
// Block 512 thr (8 waves, 128 t-rows). Grid (8, 64).
// ---------------------------------------------------------------------------
__global__ __launch_bounds__(512, 4) void ssa_v3f(
    const float* __restrict__ Qf, const float* __restrict__ Kf,
    const ushort* __restrict__ V16,
    const unsigned long long* __restrict__ SMASK,
    ushort* __restrict__ MIX16)
{
  __shared__ uint ks[64 * 36];
  __shared__ uint2 list[8][kCap];
  __shared__ float thrL[8][16];
  __shared__ unsigned long long key64L[8][16];
  __shared__ uint cnt[8];

  const int t0  = blockIdx.x << 7;
  const int bh  = blockIdx.y;
  const int tid = threadIdx.x;
  const int w    = tid >> 6;
  const int l    = tid & 63;
  const int l15  = l & 15;
  const int quad = l >> 4;

  if (tid < 8) cnt[tid] = 0;
  if (tid < 128) ((unsigned long long*)key64L)[tid] = 0ull;

  const float* Qh = Qf + (size_t)bh * (kSeq * kHD);
  const float* Kh = Kf + (size_t)bh * (kSeq * kHD);

  FragU qf0, qf1;
  {
    const float* qrow = Qh + (size_t)(t0 + (w << 4) + l15) * kHD;
    float4 q0 = *(const float4*)(qrow + (quad << 3));
    float4 q1 = *(const float4*)(qrow + (quad << 3) + 4);
    float4 q2 = *(const float4*)(qrow + 32 + (quad << 3));
    float4 q3 = *(const float4*)(qrow + 32 + (quad << 3) + 4);
    qf0.u4 = make_uint4(pack2(q0.x * kScale, q0.y * kScale),
                        pack2(q0.z * kScale, q0.w * kScale),
                        pack2(q1.x * kScale, q1.y * kScale),
                        pack2(q1.z * kScale, q1.w * kScale));
    qf1.u4 = make_uint4(pack2(q2.x * kScale, q2.y * kScale),
                        pack2(q2.z * kScale, q2.w * kScale),
                        pack2(q3.x * kScale, q3.y * kScale),
                        pack2(q3.z * kScale, q3.w * kScale));
  }

  float m4[4] = {-FLT_MAX, -FLT_MAX, -FLT_MAX, -FLT_MAX};

  // K staging: thread (krow, kc) packs d = kc*8 .. +7 of row krow from fp32
  const int krow = tid >> 3, kc = tid & 7;
  const float* kp0 = Kh + (size_t)krow * kHD + (kc << 3);
  float4 pkf0 = ((const float4*)kp0)[0];
  float4 pkf1 = ((const float4*)kp0)[1];

  for (int s0 = 0, tile = 0; s0 < kSeq; s0 += 64, ++tile) {
    __syncthreads();
    {
      uint4 w0 = make_uint4(pack2(pkf0.x, pkf0.y), pack2(pkf0.z, pkf0.w),
                            pack2(pkf1.x, pkf1.y), pack2(pkf1.z, pkf1.w));
      *(uint4*)(ks + krow * 36 + (kc << 2)) = w0;
    }
    __syncthreads();

    if (s0 + 64 < kSeq) {
      const float* kn = Kh + (size_t)(s0 + 64 + krow) * kHD + (kc << 3);
      pkf0 = ((const float4*)kn)[0];
      pkf1 = ((const float4*)kn)[1];
    }

    unsigned long long wv[4];
#pragma unroll
    for (int r = 0; r < 4; ++r)
      wv[r] = SMASK[(size_t)(t0 + (w << 4) + (quad << 2) + r) * 16 + tile];

    f32x4 sv[4];
#pragma unroll
    for (int st = 0; st < 4; ++st) {
      f32x4 sacc = (f32x4){0.f, 0.f, 0.f, 0.f};
      const int srow = (st << 4) + l15;
      FragU kf0, kf1;
      kf0.u4 = *(const uint4*)(ks + srow * 36 + (quad << 2));
      kf1.u4 = *(const uint4*)(ks + srow * 36 + 16 + (quad << 2));
      sacc = __builtin_amdgcn_mfma_f32_16x16x32_bf16(qf0.f, kf0.f, sacc, 0, 0, 0);
      sacc = __builtin_amdgcn_mfma_f32_16x16x32_bf16(qf1.f, kf1.f, sacc, 0, 0, 0);
      sv[st] = sacc;
#pragma unroll
      for (int r = 0; r < 4; ++r) {
        const uint bit = (uint)(wv[r] >> ((st << 4) + l15)) & 1u;
        if (bit) m4[r] = fmaxf(m4[r], sacc[r]);
      }
    }
    // cross-lane running max (16 lanes per row share lane bits 0..3)
#pragma unroll
    for (int r = 0; r < 4; ++r) {
      float m = m4[r];
      m = fmaxf(m, __shfl_xor(m, 1));
      m = fmaxf(m, __shfl_xor(m, 2));
      m = fmaxf(m, __shfl_xor(m, 4));
      m = fmaxf(m, __shfl_xor(m, 8));
      m4[r] = m;
    }
    // record candidates vs tightened running threshold (superset of final)
#pragma unroll
    for (int st = 0; st < 4; ++st) {
#pragma unroll
      for (int r = 0; r < 4; ++r) {
        const uint bit = (uint)(wv[r] >> ((st << 4) + l15)) & 1u;
        const float x = sv[st][r];
        if (bit && x >= m4[r] - kMargin) {
          uint idx = atomicAdd(&cnt[w], 1u);
          if (idx < (uint)kCap) {
            const int rowid = (quad << 2) + r;
            const int s = s0 + (st << 4) + l15;
            list[w][idx] = make_uint2(__float_as_uint(x),
                                      ((uint)rowid << 10) | (uint)s);
          }
        }
      }
    }
  }

  // final thresholds to LDS
  if (l15 == 0) {
#pragma unroll
    for (int r = 0; r < 4; ++r) thrL[w][(quad << 2) + r] = m4[r] - kMargin;
  }
  __syncthreads();

  // verify survivors with the EXACT R1-order fp32 dot
  const uint n = min(cnt[w], (uint)kCap);
  for (uint base = 0; base < n; base += 64) {
    const uint e = base + (uint)l;
    if (e < n) {
      const uint2 ent = list[w][e];
      const uint rowid = ent.y >> 10;
      const uint s = ent.y & 1023u;
      const float xv = __uint_as_float(ent.x);
      if (xv >= thrL[w][rowid]) {
        const int t = t0 + (w << 4) + (int)rowid;
        const float* qe = Qh + (size_t)t * kHD;
        const float* ke = Kh + (size_t)s * kHD;
        float p0 = 0.f, p1 = 0.f, p2 = 0.f, p3 = 0.f;
#pragma unroll
        for (int i = 0; i < 16; ++i) {
          float4 qq = *(const float4*)(qe + (i << 2));
          float4 kk = *(const float4*)(ke + (i << 2));
          p0 = fmaf(qq.x, kk.x, p0);
          p1 = fmaf(qq.y, kk.y, p1);
          p2 = fmaf(qq.z, kk.z, p2);
          p3 = fmaf(qq.w, kk.w, p3);
        }
        const float acc = ((p0 + p1) + (p2 + p3)) * kScale;
        const unsigned long long key =
            ((unsigned long long)monokey(acc) << 16) |
            (unsigned long long)(1023u - s);
        atomicMax(&key64L[w][rowid], key);
      }
    }
  }
  __syncthreads();

  // gather v16[argmax] into MIX16 (RMW; sca has completed)
  const int b = bh >> 3, h = bh & 7;
  const uint* Vu = (const uint*)V16 + (size_t)bh * (kSeq * 32);
#pragma unroll
  for (int r = 0; r < 4; ++r) {
    const int rowid = (quad << 2) + r;
    const unsigned long long key = key64L[w][rowid];
    const uint s = 1023u - (uint)(key & 0xFFFFull);
    const uint2 vv = *(const uint2*)(Vu + (size_t)s * 32 + (l15 << 1));
    const int t = t0 + (w << 4) + rowid;
    uint* op = (uint*)MIX16 + ((size_t)(t * kBsz + b) * kEmb + (h << 6)) / 2 + (l15 << 1);
    uint2 o = *(uint2*)op;
    float o0 = bf2f(o.x & 0xFFFF) + kT2 * bf2f(vv.x & 0xFFFF);
    float o1 = bf2f(o.x >> 16)    + kT2 * bf2f(vv.x >> 16);
    float o2 = bf2f(o.y & 0xFFFF) + kT2 * bf2f(vv.y & 0xFFFF);
    float o3 = bf2f(o.y >> 16)    + kT2 * bf2f(vv.y >> 16);
    *(uint2*)op = make_uint2(pack2(o0, o1), pack2(o2, o3));
  }
}

// ---------------------------------------------------------------------------
// Out-projection GEMM: A = MIX16 bf16 direct, B = pre-packed Wo16 direct.
// Tile 128x64, BK=32, 4 waves, fp32 out.
// ---------------------------------------------------------------------------
__global__ __launch_bounds__(256, 4) void gemm_out16(
    const ushort* __restrict__ MIX16, const ushort* __restrict__ Wo16,
    const float* __restrict__ bias, float* __restrict__ OutF)
{
  __shared__ uint As[128 * 20];
  __shared__ uint Bs[64 * 20];

  const int mBase = blockIdx.x << 7;
  const int nBase = blockIdx.y << 6;
  const int tid = threadIdx.x;
  const int w = tid >> 6;
  const int l = tid & 63;
  const int l15 = l & 15;
  const int quad = l >> 4;
  const int wm = w & 1, wn = w >> 1;

  const int srow = tid >> 1;
  const int shalf = tid & 1;

  f32x4 acc[4][2];
#pragma unroll
  for (int mi = 0; mi < 4; ++mi)
#pragma unroll
    for (int ni = 0; ni < 2; ++ni) acc[mi][ni] = (f32x4){0.f, 0.f, 0.f, 0.f};

  uint4 qa0, qa1, qb0, qb1;

#define GLOADO(kk) do {                                                    \
    const uint* ma_ = (const uint*)MIX16 + (size_t)(mBase + srow) * 256 +  \
                      ((kk) >> 1) + (shalf << 3);                          \
    qa0 = ((const uint4*)ma_)[0];                                          \
    qa1 = ((const uint4*)ma_)[1];                                          \
    if (tid < 128) {                                                       \
      const uint* ws_ = (const uint*)Wo16 + (size_t)(nBase + srow) * 256 + \
                        ((kk) >> 1) + (shalf << 3);                        \
      qb0 = ((const uint4*)ws_)[0];                                        \
      qb1 = ((const uint4*)ws_)[1];                                        \
    }                                                                      \
  } while (0)

  GLOADO(0);

  for (int k0 = 0; k0 < kEmb; k0 += 32) {
    uint4 ah0 = qa0, ah1 = qa1, bw0 = qb0, bw1 = qb1;
    __syncthreads();
    {
      uint* dst = As + srow * 20 + (shalf << 3);
      ((uint4*)dst)[0] = ah0;
      ((uint4*)dst)[1] = ah1;
      if (tid < 128) {
        uint* db = Bs + srow * 20 + (shalf << 3);
        ((uint4*)db)[0] = bw0;
        ((uint4*)db)[1] = bw1;
      }
    }
    __syncthreads();

    if (k0 + 32 < kEmb) GLOADO(k0 + 32);

    FragU aF[4], bF[2];
#pragma unroll
    for (int ni = 0; ni < 2; ++ni)
      bF[ni].u4 = *(const uint4*)(Bs + ((wn << 5) + (ni << 4) + l15) * 20 + (quad << 2));
#pragma unroll
    for (int mi = 0; mi < 4; ++mi)
      aF[mi].u4 = *(const uint4*)(As + ((wm << 6) + (mi << 4) + l15) * 20 + (quad << 2));
#pragma unroll
    for (int mi = 0; mi < 4; ++mi)
#pragma unroll
      for (int ni = 0; ni < 2; ++ni)
        acc[mi][ni] = __builtin_amdgcn_mfma_f32_16x16x32_bf16(
            aF[mi].f, bF[ni].f, acc[mi][ni], 0, 0, 0);
  }
#undef GLOADO

#pragma unroll
  for (int ni = 0; ni < 2; ++ni) {
    const int n = nBase + (wn << 5) + (ni << 4) + l15;
    const float bv = bias[n];
#pragma unroll
    for (int mi = 0; mi < 4; ++mi) {
#pragma unroll
      for (int r = 0; r < 4; ++r) {
        const int m = mBase + (wm << 6) + (mi << 4) + (quad << 2) + r;
        const float v = acc[mi][ni][r] + bv;
        OutF[(size_t)m * kEmb + n] = v;
      }
    }
  }
}

extern "C" void kernel_launch(void* const* d_in, const int* in_sizes, int n_in,
                              void* d_out, int out_size, void* d_ws, size_t ws_size,
                              hipStream_t stream) {
  const float* query  = (const float*)d_in[0];
  const float* key    = (const float*)d_in[1];
  const float* value  = (const float*)d_in[2];
  const float* qsem   = (const float*)d_in[3];
  const float* ksem   = (const float*)d_in[4];
  const float* semmap = (const float*)d_in[5];
  const float* Wi     = (const float*)d_in[6];
  const float* bi     = (const float*)d_in[7];
  const float* Wo     = (const float*)d_in[8];
  const float* bo     = (const float*)d_in[9];
  float* out = (float*)d_out;

  char* ws = (char*)d_ws;
  unsigned long long* SMASK = (unsigned long long*)ws;           ws += 1024 * 16 * 8;
  ushort* Q16   = (ushort*)ws; ws += (size_t)64 * kSeq * kHD * 2;   // 8 MB
  ushort* K16   = (ushort*)ws; ws += (size_t)64 * kSeq * kHD * 2;   // 8 MB
  ushort* V16   = (ushort*)ws; ws += (size_t)64 * kSeq * kHD * 2;   // 8 MB
  ushort* MIX16 = (ushort*)ws; ws += (size_t)kSeq * kBsz * kEmb * 2; // 8 MB
  ushort* Wi16  = (ushort*)ws; ws += (size_t)3 * kEmb * kEmb * 2;   // 1.5 MB
  ushort* Wo16  = (ushort*)ws; ws += (size_t)kEmb * kEmb * 2;       // 0.5 MB
  // Region R: X16 (24 MB, used by prepack+gemm_sca16) overlaps P1 (16 MB,
  // written by proj AFTER gemm_sca16 completes — stream-ordered).
  ushort* X16 = (ushort*)ws;
  float*  P1  = (float*)ws;    ws += (size_t)3 * kSeq * kBsz * kEmb * 2; // 24 MB
  float* P0 = out;   // d_out is dead until gemm_out16: use as fp32 Q proj

  const dim3 gpk(2048, 5);   // prepack: z = qsem/ksem/value/Wi/Wo
  const dim3 gp(64, 8, 2);   // fp32 proj grid (128x64 tiles, z = q/k)
  const dim3 g3(64, 8, 3);   // bf16 gemm grid, z = qsem/ksem/value
  const dim3 go(64, 8);      // out-proj grid
  const dim3 gs(16, 64);     // sca: t-tile x bh
  const dim3 gv(8, 64);      // ssa: 128-row t-tile x bh

  // fp32 -> bf16 prepack (bit-identical RNE to in-kernel packing)
  prepack<<<gpk, 256, 0, stream>>>(qsem, ksem, value, Wi, Wo,
                                   X16, Wi16, Wo16);
  smask_prep<<<1024, 256, 0, stream>>>(semmap, SMASK);
  // SCA projections (bf16 MFMA, direct bf16 staging)
  gemm_sca16<<<g3, 256, 0, stream>>>(X16, Wi16, bi, Q16);
  // SSA fp32 projections (no shadows) — overwrites R with P1 after gemm_sca16
  proj_ns<<<gp, 256, 0, stream>>>(query, key, Wi, bi, P0, P1);
  // SCA attention -> MIX16 = bf16(T1 * o_sca)
  sca_mfma2<<<gs, 64 * 4, 0, stream>>>(Q16, K16, V16, SMASK, MIX16);
  // SSA screen+verify -> MIX16 += bf16(T2 * v[argmax])
  ssa_v3f<<<gv, 512, 0, stream>>>(P0, P1, V16, SMASK, MIX16);
  // Out projection (direct bf16 staging)
  gemm_out16<<<go, 256, 0, stream>>>(MIX16, Wo16, bo, out);
}

// Round 11
// 369.104 us; speedup vs baseline: 1.1540x; 1.0873x over previous
//
#include <hip/hip_runtime.h>
#include <float.h>

// ---------------------------------------------------------------------------
// Fused dual-attention (SCA + SSA).  SEQ=1024, B=8, E=512, H=8, HD=64.
//
//  R16 changes:
//   * gemm_sca16b: SCA projection GEMM re-tiled 128x64 -> 128x128
//     (acc[4][4]/wave, 16 MFMA per 2-barrier chunk vs 8; B staged by all
//     256 threads). Budget forensics put the old kernel at ~80-120 us
//     (just under the top-5 cutoff) with ~25% MFMA density. Per-output
//     MFMA chain unchanged -> bit-identical Q16/K16/V16.
//     grid (64,4,3) = 768 blocks = 3 blocks/CU, launch_bounds(256,3).
//   * smask merged into prepack (grid.y = 6, z=5 branch) — one less launch.
//   * everything else = R15 (harness-verified at 401.3 us).
// ---------------------------------------------------------------------------

namespace {
constexpr int kSeq = 1024;
constexpr int kBsz = 8;
constexpr int kEmb = 512;
constexpr int kHD  = 64;
constexpr float kT1 = 0.6f;
constexpr float kT2 = 0.4f;
constexpr float kScale = 0.125f;   // 1/sqrt(64), exact pow2
constexpr float kMargin = 0.125f;  // >> 6.5-sigma bf16 score error (~0.018)
constexpr int kCap = 256;          // per-wave candidate list capacity
}

typedef short bf16x8 __attribute__((ext_vector_type(8)));
typedef float f32x4  __attribute__((ext_vector_type(4)));

union FragU { uint4 u4; bf16x8 f; uint u[4]; };

__device__ __forceinline__ ushort f2bf(float f) {
  uint u = __float_as_uint(f);
  u += 0x7fff + ((u >> 16) & 1);        // RNE
  return (ushort)(u >> 16);
}
__device__ __forceinline__ uint pack2(float lo, float hi) {
  return (uint)f2bf(lo) | ((uint)f2bf(hi) << 16);
}
__device__ __forceinline__ float bf2f(uint h) {     // h = low 16 bits
  return __uint_as_float(h << 16);
}
__device__ __forceinline__ uint monokey(float v) {
  uint u = __float_as_uint(v);
  return (u & 0x80000000u) ? ~u : (u | 0x80000000u);
}

// ---------------------------------------------------------------------------
// prepack: fp32 -> bf16 (RNE, identical bits to in-kernel pack) + smask.
// z 0..2: X inputs; z=3: Wi; z=4: Wo; z=5: sem_map -> SMASK bitmask.
// ---------------------------------------------------------------------------
__global__ __launch_bounds__(256, 8) void prepack(
    const float* __restrict__ X0, const float* __restrict__ X1,
    const float* __restrict__ X2, const float* __restrict__ Wif,
    const float* __restrict__ Wof, const float* __restrict__ SEM,
    ushort* __restrict__ X16, ushort* __restrict__ Wi16,
    ushort* __restrict__ Wo16, unsigned long long* __restrict__ SMASK)
{
  const int z = blockIdx.y;
  if (z == 5) {   // smask
    const int t = blockIdx.x;
    if (t >= 1024) return;
    const int w4 = threadIdx.x >> 6;
    const int lane = threadIdx.x & 63;
#pragma unroll
    for (int i = 0; i < 4; ++i) {
      const int word = (w4 << 2) + i;
      const float v = SEM[t * kSeq + (word << 6) + lane];
      unsigned long long m = __ballot(v >= 0.5f);
      if (lane == 0) SMASK[t * 16 + word] = m;
    }
    return;
  }

  const float* src;
  ushort* dst;
  size_t count;
  if (z == 0)      { src = X0;  dst = X16;                count = 4194304; }
  else if (z == 1) { src = X1;  dst = X16 + 4194304;      count = 4194304; }
  else if (z == 2) { src = X2;  dst = X16 + 2 * 4194304;  count = 4194304; }
  else if (z == 3) { src = Wif; dst = Wi16;               count = 786432; }
  else             { src = Wof; dst = Wo16;               count = 262144; }

  const size_t idx = ((size_t)blockIdx.x * 256 + threadIdx.x) * 8;
  if (idx >= count) return;
  float4 f0 = *(const float4*)(src + idx);
  float4 f1 = *(const float4*)(src + idx + 4);
  uint4 o = make_uint4(pack2(f0.x, f0.y), pack2(f0.z, f0.w),
                       pack2(f1.x, f1.y), pack2(f1.z, f1.w));
  *(uint4*)(dst + idx) = o;
}

// ---------------------------------------------------------------------------
// fp32 proj GEMM (no shadows) — per-element math byte-identical to R1:
// single accumulator, fma chain k=0..511 ascending, then +bias.
// Tile 128x64, 256 thr, 8x4/thread, BK=32, reg-prefetch. grid (64,8,2).
// [R14/R15 harness-verified: ~125 us — at its LDS-pipe structural floor]
// ---------------------------------------------------------------------------
__global__ __launch_bounds__(256, 4) void proj_ns(
    const float* __restrict__ Xq, const float* __restrict__ Xk,
    const float* __restrict__ W, const float* __restrict__ bias,
    float* __restrict__ OutQ, float* __restrict__ OutK)
{
  __shared__ float As[32 * 132];   // [k][m], 128 m + pad 4
  __shared__ float Bs[32 * 68];    // [k][n], 64 n + pad 4

  const int z = blockIdx.z;
  const float* X = z ? Xk : Xq;
  float* Out = z ? OutK : OutQ;
  const int woff = z << 9;

  const int mBase = blockIdx.x << 7;
  const int nBase = blockIdx.y << 6;
  const int tid = threadIdx.x;
  const int tx = tid & 15;
  const int my = tid >> 4;
  const int ar = tid >> 1, ah = (tid & 1) << 4;
  const int br = tid >> 2, bk = (tid & 3) << 3;

  float acc[8][4];
#pragma unroll
  for (int i = 0; i < 8; ++i)
#pragma unroll
    for (int j = 0; j < 4; ++j) acc[i][j] = 0.f;

  const float* xp = X + (size_t)(mBase + ar) * kEmb + ah;
  const float* wp = W + (size_t)(woff + nBase + br) * kEmb + bk;

  float4 a0 = ((const float4*)xp)[0];
  float4 a1 = ((const float4*)xp)[1];
  float4 a2 = ((const float4*)xp)[2];
  float4 a3 = ((const float4*)xp)[3];
  float4 b0 = ((const float4*)wp)[0];
  float4 b1 = ((const float4*)wp)[1];

  for (int k0 = 0; k0 < kEmb; k0 += 32) {
    __syncthreads();
    {
      float av[16] = {a0.x, a0.y, a0.z, a0.w, a1.x, a1.y, a1.z, a1.w,
                      a2.x, a2.y, a2.z, a2.w, a3.x, a3.y, a3.z, a3.w};
#pragma unroll
      for (int i = 0; i < 16; ++i) As[(ah + i) * 132 + ar] = av[i];
      float bv[8] = {b0.x, b0.y, b0.z, b0.w, b1.x, b1.y, b1.z, b1.w};
#pragma unroll
      for (int i = 0; i < 8; ++i) Bs[(bk + i) * 68 + br] = bv[i];
    }
    __syncthreads();

    const int kn = k0 + 32;
    if (kn < kEmb) {
      a0 = ((const float4*)(xp + kn))[0];
      a1 = ((const float4*)(xp + kn))[1];
      a2 = ((const float4*)(xp + kn))[2];
      a3 = ((const float4*)(xp + kn))[3];
      b0 = ((const float4*)(wp + kn))[0];
      b1 = ((const float4*)(wp + kn))[1];
    }

#pragma unroll 8
    for (int k = 0; k < 32; ++k) {
      float4 A0 = *(const float4*)&As[k * 132 + (my << 3)];
      float4 A1 = *(const float4*)&As[k * 132 + (my << 3) + 4];
      float4 Bv = *(const float4*)&Bs[k * 68 + (tx << 2)];
      float aa[8] = {A0.x, A0.y, A0.z, A0.w, A1.x, A1.y, A1.z, A1.w};
      float bb[4] = {Bv.x, Bv.y, Bv.z, Bv.w};
#pragma unroll
      for (int i = 0; i < 8; ++i)
#pragma unroll
        for (int j = 0; j < 4; ++j)
          acc[i][j] = fmaf(aa[i], bb[j], acc[i][j]);
    }
  }

#pragma unroll
  for (int i = 0; i < 8; ++i) {
    const int m = mBase + (my << 3) + i;
#pragma unroll
    for (int j = 0; j < 4; ++j) {
      const int n = nBase + (tx << 2) + j;
      const float v = acc[i][j] + bias[woff + n];
      const int oi = (((m & 7) << 3) + (n >> 6)) * (kSeq * kHD) +
                     ((m >> 3) << 6) + (n & 63);
      Out[oi] = v;
    }
  }
}

// ---------------------------------------------------------------------------
// SCA-proj GEMM (bf16 MFMA), 128x128 tile: A from X16 slab z, B from Wi16.
// acc[4][4]/wave (2x2 waves x 64x64 each); 16 MFMA per chunk; BK=32.
// grid (64,4,3) = 768 blocks = 3 blocks/CU. Direct uint4 staging.
// Per-output MFMA chain identical to the 128x64 version -> same bits.
// ---------------------------------------------------------------------------
__global__ __launch_bounds__(256, 3) void gemm_sca16b(
    const ushort* __restrict__ X16, const ushort* __restrict__ Wi16,
    const float* __restrict__ bias, ushort* __restrict__ Out16)
{
  __shared__ uint As[128 * 20];
  __shared__ uint Bs[128 * 20];

  const int z = blockIdx.z;
  const int woff = z << 9;
  const float scale = (z == 0) ? kScale : 1.0f;
  const size_t zoff = (size_t)z * ((size_t)kSeq * kBsz * kEmb);
  const uint* Xu = (const uint*)X16 + (size_t)z * (8192 * 256);
  const uint* Wu = (const uint*)Wi16;

  const int mBase = blockIdx.x << 7;
  const int nBase = blockIdx.y << 7;
  const int tid = threadIdx.x;
  const int w = tid >> 6;
  const int l = tid & 63;
  const int l15 = l & 15;
  const int quad = l >> 4;
  const int wm = w & 1, wn = w >> 1;

  const int srow = tid >> 1;         // staging row 0..127 (A and B)
  const int shalf = tid & 1;

  f32x4 acc[4][4];
#pragma unroll
  for (int mi = 0; mi < 4; ++mi)
#pragma unroll
    for (int ni = 0; ni < 4; ++ni) acc[mi][ni] = (f32x4){0.f, 0.f, 0.f, 0.f};

  uint4 qa0, qa1, qb0, qb1;

#define GLOAD16(kk) do {                                                   \
    const uint* xs_ = Xu + (size_t)(mBase + srow) * 256 + ((kk) >> 1) +    \
                      (shalf << 3);                                        \
    qa0 = ((const uint4*)xs_)[0];                                          \
    qa1 = ((const uint4*)xs_)[1];                                          \
    const uint* ws_ = Wu + (size_t)(woff + nBase + srow) * 256 +           \
                      ((kk) >> 1) + (shalf << 3);                          \
    qb0 = ((const uint4*)ws_)[0];                                          \
    qb1 = ((const uint4*)ws_)[1];                                          \
  } while (0)

  GLOAD16(0);

  for (int k0 = 0; k0 < kEmb; k0 += 32) {
    uint4 ah0 = qa0, ah1 = qa1, bw0 = qb0, bw1 = qb1;
    __syncthreads();
    {
      uint* dst = As + srow * 20 + (shalf << 3);
      ((uint4*)dst)[0] = ah0;
      ((uint4*)dst)[1] = ah1;
      uint* db = Bs + srow * 20 + (shalf << 3);
      ((uint4*)db)[0] = bw0;
      ((uint4*)db)[1] = bw1;
    }
    __syncthreads();

    if (k0 + 32 < kEmb) GLOAD16(k0 + 32);

    FragU aF[4], bF[4];
#pragma unroll
    for (int ni = 0; ni < 4; ++ni)
      bF[ni].u4 = *(const uint4*)(Bs + ((wn << 6) + (ni << 4) + l15) * 20 + (quad << 2));
#pragma unroll
    for (int mi = 0; mi < 4; ++mi)
      aF[mi].u4 = *(const uint4*)(As + ((wm << 6) + (mi << 4) + l15) * 20 + (quad << 2));
#pragma unroll
    for (int mi = 0; mi < 4; ++mi)
#pragma unroll
      for (int ni = 0; ni < 4; ++ni)
        acc[mi][ni] = __builtin_amdgcn_mfma_f32_16x16x32_bf16(
            aF[mi].f, bF[ni].f, acc[mi][ni], 0, 0, 0);
  }
#undef GLOAD16

#pragma unroll
  for (int ni = 0; ni < 4; ++ni) {
    const int n = nBase + (wn << 6) + (ni << 4) + l15;
    const float bv = bias[woff + n];
#pragma unroll
    for (int mi = 0; mi < 4; ++mi) {
#pragma unroll
      for (int r = 0; r < 4; ++r) {
        const int m = mBase + (wm << 6) + (mi << 4) + (quad << 2) + r;
        const float v = acc[mi][ni][r] + bv;
        const int oi = (((m & 7) << 3) + (n >> 6)) * (kSeq * kHD) +
                       ((m >> 3) << 6) + (n & 63);
        Out16[zoff + oi] = f2bf(v * scale);
      }
    }
  }
}

// ---------------------------------------------------------------------------
// SCA: bf16 Q16 (pre-scaled) / K16 / V16, SMASK bits, MIX16 out.
// [R12/R15 harness-verified body]  grid (16,64), 256 thr.
// ---------------------------------------------------------------------------
__global__ __launch_bounds__(256, 4) void sca_mfma2(
    const ushort* __restrict__ Q16, const ushort* __restrict__ K16,
    const ushort* __restrict__ V16,
    const unsigned long long* __restrict__ SMASK,
    ushort* __restrict__ MIX16)
{
  __shared__ uint ks[64 * 36];
  __shared__ uint vt[64 * 36];
  __shared__ uint ps[4][16 * 36];

  const int t0  = blockIdx.x << 6;
  const int bh  = blockIdx.y;
  const int tid = threadIdx.x;
  const int w    = tid >> 6;
  const int l    = tid & 63;
  const int l15  = l & 15;
  const int quad = l >> 4;

  const uint* Qu = (const uint*)Q16 + (size_t)bh * (kSeq * 32);
  const uint* Ku = (const uint*)K16 + (size_t)bh * (kSeq * 32);
  const uint* Vu = (const uint*)V16 + (size_t)bh * (kSeq * 32);

  FragU qf0, qf1;
  {
    const uint* qrow = Qu + (size_t)(t0 + (w << 4) + l15) * 32;
    qf0.u4 = *(const uint4*)(qrow + (quad << 2));
    qf1.u4 = *(const uint4*)(qrow + 16 + (quad << 2));
  }

  f32x4 oacc[4];
#pragma unroll
  for (int nt = 0; nt < 4; ++nt) oacc[nt] = (f32x4){0.f, 0.f, 0.f, 0.f};
  float den[4] = {0.f, 0.f, 0.f, 0.f};

  uint* psw = ps[w];

  const int sl = tid >> 2, c = tid & 3;    // K tile
  const int p = tid >> 3, c7 = tid & 7;    // V tile

  uint4 pk0 = ((const uint4*)(Ku + (size_t)sl * 32 + (c << 3)))[0];
  uint4 pk1 = ((const uint4*)(Ku + (size_t)sl * 32 + (c << 3)))[1];
  uint4 pv0 = *(const uint4*)(Vu + (size_t)(p << 1) * 32 + (c7 << 2));
  uint4 pv1 = *(const uint4*)(Vu + (size_t)(p << 1) * 32 + (c7 << 2) + 32);

  for (int s0 = 0, tile = 0; s0 < kSeq; s0 += 64, ++tile) {
    __syncthreads();
    {
      uint* dst = ks + sl * 36 + (c << 3);
      ((uint4*)dst)[0] = pk0;
      ((uint4*)dst)[1] = pk1;
    }
    {
      FragU A, B;
      A.u4 = pv0;
      B.u4 = pv1;
      const int Wp = (p + ((c7 & 3) << 2)) & 31;
#pragma unroll
      for (int i = 0; i < 8; ++i) {
        uint ai = (A.u[i >> 1] >> ((i & 1) << 4)) & 0xFFFF;
        uint bi = (B.u[i >> 1] >> ((i & 1) << 4)) & 0xFFFF;
        vt[((c7 << 3) + i) * 36 + Wp] = ai | (bi << 16);
      }
    }
    __syncthreads();

    if (s0 + 64 < kSeq) {
      const uint* kp = Ku + (size_t)(s0 + 64 + sl) * 32 + (c << 3);
      pk0 = ((const uint4*)kp)[0];
      pk1 = ((const uint4*)kp)[1];
      const uint* va = Vu + (size_t)(s0 + 64 + (p << 1)) * 32 + (c7 << 2);
      pv0 = *(const uint4*)va;
      pv1 = *(const uint4*)(va + 32);
    }

    unsigned long long wv[4];
#pragma unroll
    for (int r = 0; r < 4; ++r)
      wv[r] = SMASK[(size_t)(t0 + (w << 4) + (quad << 2) + r) * 16 + tile];

#pragma unroll
    for (int st = 0; st < 4; ++st) {
      f32x4 sacc = (f32x4){0.f, 0.f, 0.f, 0.f};
      const int srow = (st << 4) + l15;
      FragU kf0, kf1;
      kf0.u4 = *(const uint4*)(ks + srow * 36 + (quad << 2));
      kf1.u4 = *(const uint4*)(ks + srow * 36 + 16 + (quad << 2));
      sacc = __builtin_amdgcn_mfma_f32_16x16x32_bf16(qf0.f, kf0.f, sacc, 0, 0, 0);
      sacc = __builtin_amdgcn_mfma_f32_16x16x32_bf16(qf1.f, kf1.f, sacc, 0, 0, 0);

#pragma unroll
      for (int r = 0; r < 4; ++r) {
        const int trow = (quad << 2) + r;
        const uint bit = (uint)(wv[r] >> ((st << 4) + l15)) & 1u;
        const float val = bit ? __expf(sacc[r]) : 0.f;
        den[r] += val;
        const int W  = (st << 3) + (l15 >> 1);
        const int Wp = (W + (((trow >> 3) & 1) << 3)) & 31;
        ushort* p16 = (ushort*)(psw + trow * 36 + Wp);
        p16[l15 & 1] = f2bf(val);
      }
    }
#pragma unroll
    for (int ch = 0; ch < 2; ++ch) {
      FragU pf;
      const int pw = ((ch << 4) + (quad << 2) + (((l15 >> 3) & 1) << 3)) & 31;
      pf.u4 = *(const uint4*)(psw + l15 * 36 + pw);
#pragma unroll
      for (int nt = 0; nt < 4; ++nt) {
        const int d = (nt << 4) + l15;
        const int vw = ((ch << 4) + (quad << 2) + (((d >> 3) & 3) << 2)) & 31;
        FragU vf;
        vf.u4 = *(const uint4*)(vt + d * 36 + vw);
        oacc[nt] = __builtin_amdgcn_mfma_f32_16x16x32_bf16(pf.f, vf.f, oacc[nt], 0, 0, 0);
      }
    }
  }

#pragma unroll
  for (int r = 0; r < 4; ++r) {
    float d = den[r];
    d += __shfl_xor(d, 1);
    d += __shfl_xor(d, 2);
    d += __shfl_xor(d, 4);
    d += __shfl_xor(d, 8);
    den[r] = kT1 / d;
  }
  const int b = bh >> 3, h = bh & 7;
#pragma unroll
  for (int nt = 0; nt < 4; ++nt) {
#pragma unroll
    for (int r = 0; r < 4; ++r) {
      const int t = t0 + (w << 4) + (quad << 2) + r;
      const int d = (nt << 4) + l15;
      MIX16[(size_t)(t * kBsz + b) * kEmb + (h << 6) + d] =
          f2bf(oacc[nt][r] * den[r]);
    }
  }
}

// ---------------------------------------------------------------------------
// SSA single-pass (512-thr): bf16 MFMA screen with running cross-lane max;
// Q/K screen fragments packed on the fly from fp32 P0/P1 (identical bits to
// the old shadows); survivors get the exact fp32 dot in R1's order; per-row
// resolve via 64-bit atomicMax; RMW gather into MIX16. Grid (8, 64).
// ---------------------------------------------------------------------------
__global__ __launch_bounds__(512, 4) void ssa_v3f(
    const float* __restrict__ Qf, const float* __restrict__ Kf,
    const ushort* __restrict__ V16,
    const unsigned long long* __restrict__ SMASK,
    ushort* __restrict__ MIX16)
{
  __shared__ uint ks[64 * 36];
  __shared__ uint2 list[8][kCap];
  __shared__ float thrL[8][16];
  __shared__ unsigned long long key64L[8][16];
  __shared__ uint cnt[8];

  const int t0  = blockIdx.x << 7;
  const int bh  = blockIdx.y;
  const int tid = threadIdx.x;
  const int w    = tid >> 6;
  const int l    = tid & 63;
  const int l15  = l & 15;
  const int quad = l >> 4;

  if (tid < 8) cnt[tid] = 0;
  if (tid < 128) ((unsigned long long*)key64L)[tid] = 0ull;

  const float* Qh = Qf + (size_t)bh * (kSeq * kHD);
  const float* Kh = Kf + (size_t)bh * (kSeq * kHD);

  FragU qf0, qf1;
  {
    const float* qrow = Qh + (size_t)(t0 + (w << 4) + l15) * kHD;
    float4 q0 = *(const float4*)(qrow + (quad << 3));
    float4 q1 = *(const float4*)(qrow + (quad << 3) + 4);
    float4 q2 = *(const float4*)(qrow + 32 + (quad << 3));
    float4 q3 = *(const float4*)(qrow + 32 + (quad << 3) + 4);
    qf0.u4 = make_uint4(pack2(q0.x * kScale, q0.y * kScale),
                        pack2(q0.z * kScale, q0.w * kScale),
                        pack2(q1.x * kScale, q1.y * kScale),
                        pack2(q1.z * kScale, q1.w * kScale));
    qf1.u4 = make_uint4(pack2(q2.x * kScale, q2.y * kScale),
                        pack2(q2.z * kScale, q2.w * kScale),
                        pack2(q3.x * kScale, q3.y * kScale),
                        pack2(q3.z * kScale, q3.w * kScale));
  }

  float m4[4] = {-FLT_MAX, -FLT_MAX, -FLT_MAX, -FLT_MAX};

  // K staging: thread (krow, kc) packs d = kc*8 .. +7 of row krow from fp32
  const int krow = tid >> 3, kc = tid & 7;
  const float* kp0 = Kh + (size_t)krow * kHD + (kc << 3);
  float4 pkf0 = ((const float4*)kp0)[0];
  float4 pkf1 = ((const float4*)kp0)[1];

  for (int s0 = 0, tile = 0; s0 < kSeq; s0 += 64, ++tile) {
    __syncthreads();
    {
      uint4 w0 = make_uint4(pack2(pkf0.x, pkf0.y), pack2(pkf0.z, pkf0.w),
                            pack2(pkf1.x, pkf1.y), pack2(pkf1.z, pkf1.w));
      *(uint4*)(ks + krow * 36 + (kc << 2)) = w0;
    }
    __syncthreads();

    if (s0 + 64 < kSeq) {
      const float* kn = Kh + (size_t)(s0 + 64 + krow) * kHD + (kc << 3);
      pkf0 = ((const float4*)kn)[0];
      pkf1 = ((const float4*)kn)[1];
    }

    unsigned long long wv[4];
#pragma unroll
    for (int r = 0; r < 4; ++r)
      wv[r] = SMASK[(size_t)(t0 + (w << 4) + (quad << 2) + r) * 16 + tile];

    f32x4 sv[4];
#pragma unroll
    for (int st = 0; st < 4; ++st) {
      f32x4 sacc = (f32x4){0.f, 0.f, 0.f, 0.f};
      const int srow = (st << 4) + l15;
      FragU kf0, kf1;
      kf0.u4 = *(const uint4*)(ks + srow * 36 + (quad << 2));
      kf1.u4 = *(const uint4*)(ks + srow * 36 + 16 + (quad << 2));
      sacc = __builtin_amdgcn_mfma_f32_16x16x32_bf16(qf0.f, kf0.f, sacc, 0, 0, 0);
      sacc = __builtin_amdgcn_mfma_f32_16x16x32_bf16(qf1.f, kf1.f, sacc, 0, 0, 0);
      sv[st] = sacc;
#pragma unroll
      for (int r = 0; r < 4; ++r) {
        const uint bit = (uint)(wv[r] >> ((st << 4) + l15)) & 1u;
        if (bit) m4[r] = fmaxf(m4[r], sacc[r]);
      }
    }
    // cross-lane running max (16 lanes per row share lane bits 0..3)
#pragma unroll
    for (int r = 0; r < 4; ++r) {
      float m = m4[r];
      m = fmaxf(m, __shfl_xor(m, 1));
      m = fmaxf(m, __shfl_xor(m, 2));
      m = fmaxf(m, __shfl_xor(m, 4));
      m = fmaxf(m, __shfl_xor(m, 8));
      m4[r] = m;
    }
    // record candidates vs tightened running threshold (superset of final)
#pragma unroll
    for (int st = 0; st < 4; ++st) {
#pragma unroll
      for (int r = 0; r < 4; ++r) {
        const uint bit = (uint)(wv[r] >> ((st << 4) + l15)) & 1u;
        const float x = sv[st][r];
        if (bit && x >= m4[r] - kMargin) {
          uint idx = atomicAdd(&cnt[w], 1u);
          if (idx < (uint)kCap) {
            const int rowid = (quad << 2) + r;
            const int s = s0 + (st << 4) + l15;
            list[w][idx] = make_uint2(__float_as_uint(x),
                                      ((uint)rowid << 10) | (uint)s);
          }
        }
      }
    }
  }

  // final thresholds to LDS
  if (l15 == 0) {
#pragma unroll
    for (int r = 0; r < 4; ++r) thrL[w][(quad << 2) + r] = m4[r] - kMargin;
  }
  __syncthreads();

  // verify survivors with the EXACT R1-order fp32 dot
  const uint n = min(cnt[w], (uint)kCap);
  for (uint base = 0; base < n; base += 64) {
    const uint e = base + (uint)l;
    if (e < n) {
      const uint2 ent = list[w][e];
      const uint rowid = ent.y >> 10;
      const uint s = ent.y & 1023u;
      const float xv = __uint_as_float(ent.x);
      if (xv >= thrL[w][rowid]) {
        const int t = t0 + (w << 4) + (int)rowid;
        const float* qe = Qh + (size_t)t * kHD;
        const float* ke = Kh + (size_t)s * kHD;
        float p0 = 0.f, p1 = 0.f, p2 = 0.f, p3 = 0.f;
#pragma unroll
        for (int i = 0; i < 16; ++i) {
          float4 qq = *(const float4*)(qe + (i << 2));
          float4 kk = *(const float4*)(ke + (i << 2));
          p0 = fmaf(qq.x, kk.x, p0);
          p1 = fmaf(qq.y, kk.y, p1);
          p2 = fmaf(qq.z, kk.z, p2);
          p3 = fmaf(qq.w, kk.w, p3);
        }
        const float acc = ((p0 + p1) + (p2 + p3)) * kScale;
        const unsigned long long key =
            ((unsigned long long)monokey(acc) << 16) |
            (unsigned long long)(1023u - s);
        atomicMax(&key64L[w][rowid], key);
      }
    }
  }
  __syncthreads();

  // gather v16[argmax] into MIX16 (RMW; sca has completed)
  const int b = bh >> 3, h = bh & 7;
  const uint* Vu = (const uint*)V16 + (size_t)bh * (kSeq * 32);
#pragma unroll
  for (int r = 0; r < 4; ++r) {
    const int rowid = (quad << 2) + r;
    const unsigned long long key = key64L[w][rowid];
    const uint s = 1023u - (uint)(key & 0xFFFFull);
    const uint2 vv = *(const uint2*)(Vu + (size_t)s * 32 + (l15 << 1));
    const int t = t0 + (w << 4) + rowid;
    uint* op = (uint*)MIX16 + ((size_t)(t * kBsz + b) * kEmb + (h << 6)) / 2 + (l15 << 1);
    uint2 o = *(uint2*)op;
    float o0 = bf2f(o.x & 0xFFFF) + kT2 * bf2f(vv.x & 0xFFFF);
    float o1 = bf2f(o.x >> 16)    + kT2 * bf2f(vv.x >> 16);
    float o2 = bf2f(o.y & 0xFFFF) + kT2 * bf2f(vv.y & 0xFFFF);
    float o3 = bf2f(o.y >> 16)    + kT2 * bf2f(vv.y >> 16);
    *(uint2*)op = make_uint2(pack2(o0, o1), pack2(o2, o3));
  }
}

// ---------------------------------------------------------------------------
// Out-projection GEMM: A = MIX16 bf16 direct, B = pre-packed Wo16 direct.
// Tile 128x64, BK=32, 4 waves, fp32 out.
// ---------------------------------------------------------------------------
__global__ __launch_bounds__(256, 4) void gemm_out16(
    const ushort* __restrict__ MIX16, const ushort* __restrict__ Wo16,
    const float* __restrict__ bias, float* __restrict__ OutF)
{
  __shared__ uint As[128 * 20];
  __shared__ uint Bs[64 * 20];

  const int mBase = blockIdx.x << 7;
  const int nBase = blockIdx.y << 6;
  const int tid = threadIdx.x;
  const int w = tid >> 6;
  const int l = tid & 63;
  const int l15 = l & 15;
  const int quad = l >> 4;
  const int wm = w & 1, wn = w >> 1;

  const int srow = tid >> 1;
  const int shalf = tid & 1;

  f32x4 acc[4][2];
#pragma unroll
  for (int mi = 0; mi < 4; ++mi)
#pragma unroll
    for (int ni = 0; ni < 2; ++ni) acc[mi][ni] = (f32x4){0.f, 0.f, 0.f, 0.f};

  uint4 qa0, qa1, qb0, qb1;

#define GLOADO(kk) do {                                                    \
    const uint* ma_ = (const uint*)MIX16 + (size_t)(mBase + srow) * 256 +  \
                      ((kk) >> 1) + (shalf << 3);                          \
    qa0 = ((const uint4*)ma_)[0];                                          \
    qa1 = ((const uint4*)ma_)[1];                                          \
    if (tid < 128) {                                                       \
      const uint* ws_ = (const uint*)Wo16 + (size_t)(nBase + srow) * 256 + \
                        ((kk) >> 1) + (shalf << 3);                        \
      qb0 = ((const uint4*)ws_)[0];                                        \
      qb1 = ((const uint4*)ws_)[1];                                        \
    }                                                                      \
  } while (0)

  GLOADO(0);

  for (int k0 = 0; k0 < kEmb; k0 += 32) {
    uint4 ah0 = qa0, ah1 = qa1, bw0 = qb0, bw1 = qb1;
    __syncthreads();
    {
      uint* dst = As + srow * 20 + (shalf << 3);
      ((uint4*)dst)[0] = ah0;
      ((uint4*)dst)[1] = ah1;
      if (tid < 128) {
        uint* db = Bs + srow * 20 + (shalf << 3);
        ((uint4*)db)[0] = bw0;
        ((uint4*)db)[1] = bw1;
      }
    }
    __syncthreads();

    if (k0 + 32 < kEmb) GLOADO(k0 + 32);

    FragU aF[4], bF[2];
#pragma unroll
    for (int ni = 0; ni < 2; ++ni)
      bF[ni].u4 = *(const uint4*)(Bs + ((wn << 5) + (ni << 4) + l15) * 20 + (quad << 2));
#pragma unroll
    for (int mi = 0; mi < 4; ++mi)
      aF[mi].u4 = *(const uint4*)(As + ((wm << 6) + (mi << 4) + l15) * 20 + (quad << 2));
#pragma unroll
    for (int mi = 0; mi < 4; ++mi)
#pragma unroll
      for (int ni = 0; ni < 2; ++ni)
        acc[mi][ni] = __builtin_amdgcn_mfma_f32_16x16x32_bf16(
            aF[mi].f, bF[ni].f, acc[mi][ni], 0, 0, 0);
  }
#undef GLOADO

#pragma unroll
  for (int ni = 0; ni < 2; ++ni) {
    const int n = nBase + (wn << 5) + (ni << 4) + l15;
    const float bv = bias[n];
#pragma unroll
    for (int mi = 0; mi < 4; ++mi) {
#pragma unroll
      for (int r = 0; r < 4; ++r) {
        const int m = mBase + (wm << 6) + (mi << 4) + (quad << 2) + r;
        const float v = acc[mi][ni][r] + bv;
        OutF[(size_t)m * kEmb + n] = v;
      }
    }
  }
}

extern "C" void kernel_launch(void* const* d_in, const int* in_sizes, int n_in,
                              void* d_out, int out_size, void* d_ws, size_t ws_size,
                              hipStream_t stream) {
  const float* query  = (const float*)d_in[0];
  const float* key    = (const float*)d_in[1];
  const float* value  = (const float*)d_in[2];
  const float* qsem   = (const float*)d_in[3];
  const float* ksem   = (const float*)d_in[4];
  const float* semmap = (const float*)d_in[5];
  const float* Wi     = (const float*)d_in[6];
  const float* bi     = (const float*)d_in[7];
  const float* Wo     = (const float*)d_in[8];
  const float* bo     = (const float*)d_in[9];
  float* out = (float*)d_out;

  char* ws = (char*)d_ws;
  unsigned long long* SMASK = (unsigned long long*)ws;           ws += 1024 * 16 * 8;
  ushort* Q16   = (ushort*)ws; ws += (size_t)64 * kSeq * kHD * 2;   // 8 MB
  ushort* K16   = (ushort*)ws; ws += (size_t)64 * kSeq * kHD * 2;   // 8 MB
  ushort* V16   = (ushort*)ws; ws += (size_t)64 * kSeq * kHD * 2;   // 8 MB
  ushort* MIX16 = (ushort*)ws; ws += (size_t)kSeq * kBsz * kEmb * 2; // 8 MB
  ushort* Wi16  = (ushort*)ws; ws += (size_t)3 * kEmb * kEmb * 2;   // 1.5 MB
  ushort* Wo16  = (ushort*)ws; ws += (size_t)kEmb * kEmb * 2;       // 0.5 MB
  // Region R: X16 (24 MB, used by prepack+gemm_sca16b) overlaps P1 (16 MB,
  // written by proj AFTER gemm_sca16b completes — stream-ordered).
  ushort* X16 = (ushort*)ws;
  float*  P1  = (float*)ws;    ws += (size_t)3 * kSeq * kBsz * kEmb * 2; // 24 MB
  float* P0 = out;   // d_out is dead until gemm_out16: use as fp32 Q proj

  const dim3 gpk(2048, 6);   // prepack: z = qsem/ksem/value/Wi/Wo/smask
  const dim3 gp(64, 8, 2);   // fp32 proj grid (128x64 tiles, z = q/k)
  const dim3 g3(64, 4, 3);   // bf16 gemm grid (128x128), z = qsem/ksem/value
  const dim3 go(64, 8);      // out-proj grid
  const dim3 gs(16, 64);     // sca: t-tile x bh
  const dim3 gv(8, 64);      // ssa: 128-row t-tile x bh

  // fp32 -> bf16 prepack (bit-identical RNE) + smask
  prepack<<<gpk, 256, 0, stream>>>(qsem, ksem, value, Wi, Wo, semmap,
                                   X16, Wi16, Wo16, SMASK);
  // SCA projections (bf16 MFMA, 128x128 tile, direct bf16 staging)
  gemm_sca16b<<<g3, 256, 0, stream>>>(X16, Wi16, bi, Q16);
  // SSA fp32 projections (no shadows) — overwrites R with P1 after gemm
  proj_ns<<<gp, 256, 0, stream>>>(query, key, Wi, bi, P0, P1);
  // SCA attention -> MIX16 = bf16(T1 * o_sca)
  sca_mfma2<<<gs, 256, 0, stream>>>(Q16, K16, V16, SMASK, MIX16);
  // SSA screen+verify -> MIX16 += bf16(T2 * v[argmax])
  ssa_v3f<<<gv, 512, 0, stream>>>(P0, P1, V16, SMASK, MIX16);
  // Out projection (direct bf16 staging)
  gemm_out16<<<go, 256, 0, stream>>>(MIX16, Wo16, bo, out);
}